// Round 7
// baseline (742.269 us; speedup 1.0000x reference)
//
#include <hip/hip_runtime.h>
#include <cstdint>
#include <cstddef>

#define B_ 4
#define V1 262144   // 64^3
#define C1 64
#define V2 32768    // 32^3
#define C2 128
#define TOTV 131072            // B_*V2
#define SLICE 4194304          // TOTV*32 elements per channel-slice

// stats layout (float indices within stats buffer)
#define OFF_S1A 0
#define OFF_S2A 128
#define OFF_CNT1 256
#define OFF_S1B 260
#define OFF_S2B 388
#define OFF_CNT2 516

typedef __bf16 bf16x8 __attribute__((ext_vector_type(8)));
typedef float f32x4 __attribute__((ext_vector_type(4)));

__device__ __forceinline__ float bf2f(unsigned short u) {
    return __builtin_bit_cast(float, (unsigned)u << 16);
}
__device__ __forceinline__ unsigned short f2bf(float f) {
    unsigned u = __builtin_bit_cast(unsigned, f);
    u += 0x7fffu + ((u >> 16) & 1u);     // RTNE
    return (unsigned short)(u >> 16);
}

// ---------------- Kernel 0: weight prep -> bf16, frag-contiguous slabs ----------------
// seq = s*27 + (dz*9+dy*3+dx); skip slabs last. Within slab: [q4][n128][j8], k=q*8+j, n=co.
__global__ __launch_bounds__(256) void k0_wprep(const float* __restrict__ w1,
                                                const float* __restrict__ w2,
                                                const float* __restrict__ wskip,
                                                unsigned short* __restrict__ w1t,
                                                unsigned short* __restrict__ w2t)
{
    int i = blockIdx.x * 256 + threadIdx.x;
    if (i < 54 * 4096) {
        int seq = i >> 12, r = i & 4095;
        int q = r >> 10, n = (r >> 3) & 127, j = r & 7;
        int s = seq / 27, t = seq % 27;
        int ci = s * 32 + q * 8 + j;
        w1t[i] = f2bf(w1[((size_t)t * 64 + ci) * 128 + n]);
    }
    int i2 = i - 54 * 4096;
    if (i2 >= 0 && i2 < 110 * 4096) {
        int seq = i2 >> 12, r = i2 & 4095;
        int q = r >> 10, n = (r >> 3) & 127, j = r & 7;
        float v;
        if (seq < 108) {
            int s = seq / 27, t = seq % 27;
            int ci = s * 32 + q * 8 + j;
            v = w2[((size_t)t * 128 + ci) * 128 + n];
        } else {
            int ci = (seq - 108) * 32 + q * 8 + j;
            v = wskip[(size_t)ci * 128 + n];
        }
        w2t[i2] = f2bf(v);
    }
}

// ---------------- Kernel 1: GN1 stats ----------------
__global__ __launch_bounds__(256) void k1_stats1(const float* __restrict__ x,
                                                 const int* __restrict__ mask,
                                                 float* __restrict__ stats)
{
    __shared__ float ls1[32], ls2[32];
    __shared__ float lcnt;
    int tid = threadIdx.x;
    if (tid < 32) { ls1[tid] = 0.f; ls2[tid] = 0.f; }
    if (tid == 0) lcnt = 0.f;
    __syncthreads();

    int b  = blockIdx.x & 3;
    int bb = blockIdx.x >> 2;
    int c4 = tid & 15;
    int vl = tid >> 4;

    const float* xb = x + ((size_t)b * V1) * C1;
    const int*   mb = mask + (size_t)b * V1;

    float s1a = 0.f, s2a = 0.f, s1b = 0.f, s2b = 0.f, mc = 0.f;
    for (int ch = bb; ch < V1 / 16; ch += 1024) {
        int v = ch * 16 + vl;
        int m = mb[v];
        if (c4 == 0) mc += (float)m;
        if (m) {
            float4 xv = *(const float4*)(xb + (size_t)v * C1 + c4 * 4);
            s1a += xv.x + xv.y;  s2a += xv.x * xv.x + xv.y * xv.y;
            s1b += xv.z + xv.w;  s2b += xv.z * xv.z + xv.w * xv.w;
        }
    }
    atomicAdd(&ls1[2 * c4],     s1a); atomicAdd(&ls2[2 * c4],     s2a);
    atomicAdd(&ls1[2 * c4 + 1], s1b); atomicAdd(&ls2[2 * c4 + 1], s2b);
    if (c4 == 0) atomicAdd(&lcnt, mc);
    __syncthreads();
    if (tid < 32) {
        atomicAdd(&stats[OFF_S1A + b * 32 + tid], ls1[tid]);
        atomicAdd(&stats[OFF_S2A + b * 32 + tid], ls2[tid]);
    }
    if (tid == 0) atomicAdd(&stats[OFF_CNT1 + b], lcnt);
}

// ------ Kernel 2: GN1 apply + SiLU + downsample -> h1bs (sliced bf16), xdbs (sliced), dm ------
__global__ __launch_bounds__(256) void k2_down(const float* __restrict__ x,
                                               const int* __restrict__ mask,
                                               const float* __restrict__ gn1w,
                                               const float* __restrict__ gn1b,
                                               const float* __restrict__ stats,
                                               unsigned short* __restrict__ h1bs,
                                               unsigned short* __restrict__ xdbs,
                                               float* __restrict__ dm)
{
    int tid = threadIdx.x;
    int c  = tid & 63;
    int vl = tid >> 6;
    size_t ov = (size_t)blockIdx.x * 4 + vl;
    int b  = (int)(ov >> 15);
    int v2 = (int)(ov & 32767);
    int z = v2 >> 10, y = (v2 >> 5) & 31, xk = v2 & 31;

    int g = c >> 1;
    float ce   = fmaxf(stats[OFF_CNT1 + b] * 2.f, 1.f);
    float mean = stats[OFF_S1A + b * 32 + g] / ce;
    float var  = stats[OFF_S2A + b * 32 + g] / ce - mean * mean;
    float rinv = rsqrtf(var + 1e-5f);
    float a  = rinv * gn1w[c];
    float bc = gn1b[c] - mean * a;

    const int*   mb = mask + ((size_t)b << 18);
    const float* xb = x + (((size_t)b << 18) << 6);

    float hacc = 0.f, xacc = 0.f; int cnt = 0;
    #pragma unroll
    for (int dz = 0; dz < 2; ++dz)
    #pragma unroll
    for (int dy = 0; dy < 2; ++dy)
    #pragma unroll
    for (int dx = 0; dx < 2; ++dx) {
        int v1 = ((2 * z + dz) << 12) | ((2 * y + dy) << 6) | (2 * xk + dx);
        if (mb[v1]) {
            cnt++;
            float xv = xb[(size_t)v1 * 64 + c];
            xacc += xv;
            float yv = fmaf(xv, a, bc);
            hacc += yv / (1.f + expf(-yv));
        }
    }
    float inv = 1.f / fmaxf((float)cnt, 1.f);
    size_t so = (size_t)(c >> 5) * SLICE + ov * 32 + (c & 31);
    h1bs[so] = f2bf(hacc * inv);
    xdbs[so] = f2bf(xacc * inv);
    if (c == 0) dm[ov] = (cnt > 0) ? 1.f : 0.f;
}

// ---------------- MFMA implicit-GEMM conv 3x3x3 (+optional 1x1 skip) ----------------
// Block tile M=128 (4 y-rows at one (b,z)) x N=128. 4 waves: wm (y-pair) x wn (N-half).
// Wave tile M=64 x N=64: acc[4][4] f32x4 = 64 VGPR.
// A staged in LDS per (s,dz) superstep from channel-sliced source (contiguous 64B/voxel),
// stride-80B records (bank-uniform). B frags per-lane direct from global (L2-hot),
// prefetched 1 tap ahead. Barriers: 2 per superstep only.
template<int CIN, bool SKIP>
__global__ __launch_bounds__(256, 4) void conv3_mfma(
    const unsigned short* __restrict__ srcS,   // [CS][TOTV][32]
    const unsigned short* __restrict__ skipS,  // [2][TOTV][32] or null
    const unsigned short* __restrict__ wT,
    const float* __restrict__ bias,
    const float* __restrict__ bias2,
    const float* __restrict__ dm,
    float* __restrict__ outf,
    unsigned short* __restrict__ outb)
{
    constexpr int CS   = CIN / 32;
    constexpr int NKM  = 27 * CS;
    constexpr int NK   = NKM + (SKIP ? 2 : 0);
    constexpr int NSSM = 3 * CS;
    constexpr int NSS  = NSSM + (SKIP ? 2 : 0);
    constexpr int ATB  = 204 * 80;          // bytes per A-tile buffer

    __shared__ __align__(16) char aT[2 * ATB];   // ~32 KB

    const int tid  = threadIdx.x;
    const int lane = tid & 63;
    const int wv   = tid >> 6;
    const int wm   = wv >> 1;
    const int wn   = wv & 1;
    const int orig = blockIdx.x;
    const int blk  = (orig & 7) * 128 + (orig >> 3);   // bijective XCD swizzle
    const int b    = blk >> 8;
    const int z    = (blk >> 3) & 31;
    const int yo   = blk & 7;
    const int vb   = b * 32768;
    const int xl   = lane & 15;
    const int q    = lane >> 4;

    // staging geometry: thread t -> tile voxel t (t<204)
    const int syy = tid / 34, sxx = tid % 34;
    const int sy  = yo * 4 + syy - 1;
    const int sxg = sxx - 1;
    const bool svalid = (tid < 204) && ((unsigned)sy < 32u) && ((unsigned)sxg < 32u);

    const uint4* wT4 = (const uint4*)wT;
    const int bfi = wn * 64 + xl;

    const uint4 Z4 = {0, 0, 0, 0};

    f32x4 acc[4][4];
    #pragma unroll
    for (int f = 0; f < 4; ++f)
        #pragma unroll
        for (int nb = 0; nb < 4; ++nb)
            acc[f][nb] = (f32x4){0.f, 0.f, 0.f, 0.f};

    // A-read base byte offsets within a buffer (tap adds (dy*34+dx)*80)
    const int aB00 = ((wm * 2 + 0) * 34 + 0 * 16 + xl) * 80 + q * 16;
    const int aB01 = ((wm * 2 + 0) * 34 + 1 * 16 + xl) * 80 + q * 16;
    const int aB10 = ((wm * 2 + 1) * 34 + 0 * 16 + xl) * 80 + q * 16;
    const int aB11 = ((wm * 2 + 1) * 34 + 1 * 16 + xl) * 80 + q * 16;

    // staging source for superstep i (pointer always valid; ok gates the load)
    auto stage_ptr = [&](int i, bool& ok) -> const uint4* {
        int slice, zz;
        const unsigned short* base;
        if (SKIP && i >= NSSM) { slice = i - NSSM; zz = z; base = skipS; ok = svalid; }
        else {
            slice = i / 3; int dz = i % 3; zz = z + dz - 1; base = srcS;
            ok = svalid && ((unsigned)zz < 32u);
        }
        int vidx = ok ? (vb + zz * 1024 + sy * 32 + sxg) : 0;
        return (const uint4*)base + ((size_t)slice * TOTV + (size_t)vidx) * 4;
    };

    int ks = 0, cur = 0;
    uint4 bc0, bc1, bc2, bc3;

    // ---- prologue: tile 0 -> aT[0], B frags for ks=0 ----
    {
        bool ok; const uint4* p = stage_ptr(0, ok);
        uint4 s0 = Z4, s1 = Z4, s2 = Z4, s3 = Z4;
        if (ok) { s0 = p[0]; s1 = p[1]; s2 = p[2]; s3 = p[3]; }
        const uint4* wp = wT4 + q * 128 + bfi;
        bc0 = wp[0]; bc1 = wp[16]; bc2 = wp[32]; bc3 = wp[48];
        if (tid < 204) {
            uint4* d = (uint4*)(aT + tid * 80);
            d[0] = s0; d[1] = s1; d[2] = s2; d[3] = s3;
        }
        __syncthreads();
    }

    auto do_tap = [&](int ao) {
        uint4 m0 = Z4, m1 = Z4, m2 = Z4, m3 = Z4;
        if (ks + 1 < NK) {
            const uint4* wp = wT4 + (size_t)(ks + 1) * 512 + q * 128 + bfi;
            m0 = wp[0]; m1 = wp[16]; m2 = wp[32]; m3 = wp[48];
        }
        const char* aCur = aT + cur * ATB;
        bf16x8 a00 = *(const bf16x8*)(aCur + aB00 + ao);
        bf16x8 a01 = *(const bf16x8*)(aCur + aB01 + ao);
        bf16x8 a10 = *(const bf16x8*)(aCur + aB10 + ao);
        bf16x8 a11 = *(const bf16x8*)(aCur + aB11 + ao);
        bf16x8 w0 = __builtin_bit_cast(bf16x8, bc0);
        bf16x8 w1 = __builtin_bit_cast(bf16x8, bc1);
        bf16x8 w2 = __builtin_bit_cast(bf16x8, bc2);
        bf16x8 w3 = __builtin_bit_cast(bf16x8, bc3);
        acc[0][0] = __builtin_amdgcn_mfma_f32_16x16x32_bf16(a00, w0, acc[0][0], 0, 0, 0);
        acc[0][1] = __builtin_amdgcn_mfma_f32_16x16x32_bf16(a00, w1, acc[0][1], 0, 0, 0);
        acc[0][2] = __builtin_amdgcn_mfma_f32_16x16x32_bf16(a00, w2, acc[0][2], 0, 0, 0);
        acc[0][3] = __builtin_amdgcn_mfma_f32_16x16x32_bf16(a00, w3, acc[0][3], 0, 0, 0);
        acc[1][0] = __builtin_amdgcn_mfma_f32_16x16x32_bf16(a01, w0, acc[1][0], 0, 0, 0);
        acc[1][1] = __builtin_amdgcn_mfma_f32_16x16x32_bf16(a01, w1, acc[1][1], 0, 0, 0);
        acc[1][2] = __builtin_amdgcn_mfma_f32_16x16x32_bf16(a01, w2, acc[1][2], 0, 0, 0);
        acc[1][3] = __builtin_amdgcn_mfma_f32_16x16x32_bf16(a01, w3, acc[1][3], 0, 0, 0);
        acc[2][0] = __builtin_amdgcn_mfma_f32_16x16x32_bf16(a10, w0, acc[2][0], 0, 0, 0);
        acc[2][1] = __builtin_amdgcn_mfma_f32_16x16x32_bf16(a10, w1, acc[2][1], 0, 0, 0);
        acc[2][2] = __builtin_amdgcn_mfma_f32_16x16x32_bf16(a10, w2, acc[2][2], 0, 0, 0);
        acc[2][3] = __builtin_amdgcn_mfma_f32_16x16x32_bf16(a10, w3, acc[2][3], 0, 0, 0);
        acc[3][0] = __builtin_amdgcn_mfma_f32_16x16x32_bf16(a11, w0, acc[3][0], 0, 0, 0);
        acc[3][1] = __builtin_amdgcn_mfma_f32_16x16x32_bf16(a11, w1, acc[3][1], 0, 0, 0);
        acc[3][2] = __builtin_amdgcn_mfma_f32_16x16x32_bf16(a11, w2, acc[3][2], 0, 0, 0);
        acc[3][3] = __builtin_amdgcn_mfma_f32_16x16x32_bf16(a11, w3, acc[3][3], 0, 0, 0);
        bc0 = m0; bc1 = m1; bc2 = m2; bc3 = m3;
        ++ks;
    };

    #pragma clang loop unroll(disable)
    for (int i = 0; i < NSS; ++i) {
        // issue next superstep's staging loads early
        uint4 n0 = Z4, n1 = Z4, n2 = Z4, n3 = Z4;
        if (i + 1 < NSS) {
            bool ok; const uint4* p = stage_ptr(i + 1, ok);
            if (ok) { n0 = p[0]; n1 = p[1]; n2 = p[2]; n3 = p[3]; }
        }
        // compute on aT[cur]
        if (!SKIP || i < NSSM) {
            #pragma unroll
            for (int t9 = 0; t9 < 9; ++t9)
                do_tap(((t9 / 3) * 34 + (t9 % 3)) * 80);
        } else {
            do_tap((1 * 34 + 1) * 80);
        }
        __syncthreads();          // all waves done reading aT[cur^1] (superstep i-1)
        if (i + 1 < NSS && tid < 204) {
            uint4* d = (uint4*)(aT + (cur ^ 1) * ATB + tid * 80);
            d[0] = n0; d[1] = n1; d[2] = n2; d[3] = n3;
        }
        __syncthreads();          // next tile visible
        cur ^= 1;
    }

    // ---- epilogue ----
    float bv[4];
    #pragma unroll
    for (int nb = 0; nb < 4; ++nb) {
        int co = wn * 64 + nb * 16 + xl;
        if constexpr (SKIP) bv[nb] = bias[co] + bias2[co];
        else                bv[nb] = bias[co];
    }
    #pragma unroll
    for (int f = 0; f < 4; ++f) {
        const int fy = f >> 1, fx = f & 1;
        const int yrow = yo * 4 + wm * 2 + fy;
        const int xb2  = fx * 16 + q * 4;
        const int vox0 = vb + z * 1024 + yrow * 32 + xb2;
        float4 dm4 = *(const float4*)(dm + vox0);
        #pragma unroll
        for (int j = 0; j < 4; ++j) {
            const float dmx = (j == 0) ? dm4.x : (j == 1) ? dm4.y : (j == 2) ? dm4.z : dm4.w;
            const size_t obase = (size_t)(vox0 + j) * 128 + wn * 64 + xl;
            #pragma unroll
            for (int nb = 0; nb < 4; ++nb) {
                float o = (acc[f][nb][j] + bv[nb]) * dmx;
                if constexpr (SKIP) outf[obase + nb * 16] = o;
                else                outb[obase + nb * 16] = f2bf(o);
            }
        }
    }
}

// ---------------- Kernel 4: GN2 stats over h2a ([vox][128] bf16) ----------------
__global__ __launch_bounds__(256) void k4_stats2(const unsigned short* __restrict__ h2a,
                                                 const float* __restrict__ dm,
                                                 float* __restrict__ stats)
{
    __shared__ float ls1[32], ls2[32];
    __shared__ float lcnt;
    int tid = threadIdx.x;
    if (tid < 32) { ls1[tid] = 0.f; ls2[tid] = 0.f; }
    if (tid == 0) lcnt = 0.f;
    __syncthreads();

    int b  = blockIdx.x & 3;
    int bb = blockIdx.x >> 2;
    int g  = tid & 31;
    int vl = tid >> 5;

    const unsigned short* hb = h2a + ((size_t)b * V2) * C2;
    const float* dmb = dm + (size_t)b * V2;

    float s1 = 0.f, s2 = 0.f, mc = 0.f;
    for (int ch = bb; ch < V2 / 8; ch += 1024) {
        int v = ch * 8 + vl;
        float m = dmb[v];
        if (g == 0) mc += m;
        if (m != 0.f) {
            ushort4 hv = *(const ushort4*)(hb + (size_t)v * C2 + g * 4);
            float h0 = bf2f(hv.x), h1 = bf2f(hv.y), h2 = bf2f(hv.z), h3 = bf2f(hv.w);
            s1 += h0 + h1 + h2 + h3;
            s2 += h0 * h0 + h1 * h1 + h2 * h2 + h3 * h3;
        }
    }
    atomicAdd(&ls1[g], s1); atomicAdd(&ls2[g], s2);
    if (g == 0) atomicAdd(&lcnt, mc);
    __syncthreads();
    if (tid < 32) {
        atomicAdd(&stats[OFF_S1B + b * 32 + tid], ls1[tid]);
        atomicAdd(&stats[OFF_S2B + b * 32 + tid], ls2[tid]);
    }
    if (tid == 0) atomicAdd(&stats[OFF_CNT2 + b], lcnt);
}

// ---------------- Kernel 5: GN2 apply + SiLU -> h2bs (channel-sliced bf16) ----------------
__global__ __launch_bounds__(256) void k5_gn2(const unsigned short* __restrict__ h2a,
                                              unsigned short* __restrict__ h2bs,
                                              const float* __restrict__ stats,
                                              const float* __restrict__ dm,
                                              const float* __restrict__ gn2w,
                                              const float* __restrict__ gn2b)
{
    int idx = blockIdx.x * 256 + threadIdx.x;   // group-quad index
    int v = idx >> 5, g = idx & 31;
    int b = v >> 15;
    float ce   = fmaxf(stats[OFF_CNT2 + b] * 4.f, 1.f);
    float mean = stats[OFF_S1B + b * 32 + g] / ce;
    float var  = stats[OFF_S2B + b * 32 + g] / ce - mean * mean;
    float rinv = rsqrtf(var + 1e-5f);
    float dmv  = dm[v];
    ushort4 hv = *(const ushort4*)(h2a + (size_t)idx * 4);
    float4 gw = *(const float4*)(gn2w + g * 4);
    float4 gb = *(const float4*)(gn2b + g * 4);
    float a, t;
    ushort4 o;
    a = rinv * gw.x; t = (fmaf(bf2f(hv.x), a, gb.x - mean * a)) * dmv; o.x = f2bf(t / (1.f + expf(-t)));
    a = rinv * gw.y; t = (fmaf(bf2f(hv.y), a, gb.y - mean * a)) * dmv; o.y = f2bf(t / (1.f + expf(-t)));
    a = rinv * gw.z; t = (fmaf(bf2f(hv.z), a, gb.z - mean * a)) * dmv; o.z = f2bf(t / (1.f + expf(-t)));
    a = rinv * gw.w; t = (fmaf(bf2f(hv.w), a, gb.w - mean * a)) * dmv; o.w = f2bf(t / (1.f + expf(-t)));
    // channel-sliced store: channels g*4..g*4+3 -> slice g>>3, offset (g&7)*4
    *(ushort4*)(h2bs + (size_t)(g >> 3) * SLICE + (size_t)v * 32 + (g & 7) * 4) = o;
}

extern "C" void kernel_launch(void* const* d_in, const int* in_sizes, int n_in,
                              void* d_out, int out_size, void* d_ws, size_t ws_size,
                              hipStream_t stream)
{
    const float* x     = (const float*)d_in[0];
    const int*   mask  = (const int*)d_in[1];
    const float* gn1w  = (const float*)d_in[2];
    const float* gn1b  = (const float*)d_in[3];
    const float* w1    = (const float*)d_in[4];
    const float* b1    = (const float*)d_in[5];
    const float* gn2w  = (const float*)d_in[6];
    const float* gn2b  = (const float*)d_in[7];
    const float* w2    = (const float*)d_in[8];
    const float* b2    = (const float*)d_in[9];
    const float* wskip = (const float*)d_in[10];
    const float* bskip = (const float*)d_in[11];
    float* out = (float*)d_out;

    char* wsb = (char*)d_ws;
    float*          stats = (float*)wsb;                          // 520 f32
    float*          dm    = (float*)(wsb + 4096);                 // 131072 f32
    unsigned short* h1bs  = (unsigned short*)(wsb + 528384);      // [2][TOTV][32] bf16
    unsigned short* xdbs  = (unsigned short*)(wsb + 17305600);    // [2][TOTV][32] bf16
    unsigned short* h2a   = (unsigned short*)(wsb + 34082816);    // [TOTV][128] bf16
    unsigned short* h2bs  = (unsigned short*)(wsb + 67637248);    // [4][TOTV][32] bf16
    unsigned short* w1t   = (unsigned short*)(wsb + 101191680);   // 54*4096 bf16
    unsigned short* w2t   = (unsigned short*)(wsb + 101634048);   // 110*4096 bf16

    hipMemsetAsync(stats, 0, 520 * sizeof(float), stream);

    hipLaunchKernelGGL(k0_wprep, dim3(2624), dim3(256), 0, stream, w1, w2, wskip, w1t, w2t);
    hipLaunchKernelGGL(k1_stats1, dim3(4096), dim3(256), 0, stream, x, mask, stats);
    hipLaunchKernelGGL(k2_down, dim3(32768), dim3(256), 0, stream,
                       x, mask, gn1w, gn1b, stats, h1bs, xdbs, dm);
    hipLaunchKernelGGL((conv3_mfma<64, false>), dim3(1024), dim3(256), 0, stream,
                       h1bs, (const unsigned short*)nullptr, w1t, b1, (const float*)nullptr,
                       dm, (float*)nullptr, h2a);
    hipLaunchKernelGGL(k4_stats2, dim3(4096), dim3(256), 0, stream, h2a, dm, stats);
    hipLaunchKernelGGL(k5_gn2, dim3(16384), dim3(256), 0, stream, h2a, h2bs, stats, dm, gn2w, gn2b);
    hipLaunchKernelGGL((conv3_mfma<128, true>), dim3(1024), dim3(256), 0, stream,
                       h2bs, xdbs, w2t, b2, bskip, dm, out, (unsigned short*)nullptr);
}

// Round 8
// 470.548 us; speedup vs baseline: 1.5775x; 1.5775x over previous
//
#include <hip/hip_runtime.h>
#include <cstdint>
#include <cstddef>

#define B_ 4
#define V1 262144   // 64^3
#define C1 64
#define V2 32768    // 32^3
#define C2 128

// stats layout (float indices within stats buffer)
#define OFF_S1A 0
#define OFF_S2A 128
#define OFF_CNT1 256
#define OFF_S1B 260
#define OFF_S2B 388
#define OFF_CNT2 516

typedef __bf16 bf16x8 __attribute__((ext_vector_type(8)));
typedef float f32x4 __attribute__((ext_vector_type(4)));

__device__ __forceinline__ float bf2f(unsigned short u) {
    return __builtin_bit_cast(float, (unsigned)u << 16);
}
__device__ __forceinline__ unsigned short f2bf(float f) {
    unsigned u = __builtin_bit_cast(unsigned, f);
    u += 0x7fffu + ((u >> 16) & 1u);     // RTNE
    return (unsigned short)(u >> 16);
}

// T4: barrier WITHOUT vmcnt drain — LDS ordering only. Global loads stay in
// flight across it; compiler inserts counted vmcnt waits at reg-use points.
__device__ __forceinline__ void barrier_nodrain() {
    asm volatile("s_waitcnt lgkmcnt(0)" ::: "memory");
    __builtin_amdgcn_s_barrier();
}

// ---------------- Kernel 0: weight prep -> bf16, frag-contiguous slabs [q][n][j] ----------------
// W1T: 54 slabs (27 taps x 2 cslices, tap-major seq t*CS+s matches kernel loop).
// W2T: 110 slabs (27x4 conv2 + 2 skip).
__global__ __launch_bounds__(256) void k0_wprep(const float* __restrict__ w1,
                                                const float* __restrict__ w2,
                                                const float* __restrict__ wskip,
                                                unsigned short* __restrict__ w1t,
                                                unsigned short* __restrict__ w2t)
{
    int i = blockIdx.x * 256 + threadIdx.x;
    if (i < 54 * 4096) {
        int slab = i >> 12, r = i & 4095;
        int q = r >> 10, n = (r >> 3) & 127, j = r & 7;
        int t = slab >> 1, s = slab & 1;
        int ci = s * 32 + q * 8 + j;
        w1t[i] = f2bf(w1[((size_t)t * 64 + ci) * 128 + n]);
    }
    int i2 = i - 54 * 4096;
    if (i2 >= 0 && i2 < 110 * 4096) {
        int slab = i2 >> 12, r = i2 & 4095;
        int q = r >> 10, n = (r >> 3) & 127, j = r & 7;
        float v;
        if (slab < 108) {
            int t = slab >> 2, s = slab & 3;
            int ci = s * 32 + q * 8 + j;
            v = w2[((size_t)t * 128 + ci) * 128 + n];
        } else {
            int ci = (slab - 108) * 32 + q * 8 + j;
            v = wskip[(size_t)ci * 128 + n];
        }
        w2t[i2] = f2bf(v);
    }
}

// ---------------- Kernel 1: GN1 stats ----------------
__global__ __launch_bounds__(256) void k1_stats1(const float* __restrict__ x,
                                                 const int* __restrict__ mask,
                                                 float* __restrict__ stats)
{
    __shared__ float ls1[32], ls2[32];
    __shared__ float lcnt;
    int tid = threadIdx.x;
    if (tid < 32) { ls1[tid] = 0.f; ls2[tid] = 0.f; }
    if (tid == 0) lcnt = 0.f;
    __syncthreads();

    int b  = blockIdx.x & 3;
    int bb = blockIdx.x >> 2;
    int c4 = tid & 15;
    int vl = tid >> 4;

    const float* xb = x + ((size_t)b * V1) * C1;
    const int*   mb = mask + (size_t)b * V1;

    float s1a = 0.f, s2a = 0.f, s1b = 0.f, s2b = 0.f, mc = 0.f;
    for (int ch = bb; ch < V1 / 16; ch += 1024) {
        int v = ch * 16 + vl;
        int m = mb[v];
        if (c4 == 0) mc += (float)m;
        if (m) {
            float4 xv = *(const float4*)(xb + (size_t)v * C1 + c4 * 4);
            s1a += xv.x + xv.y;  s2a += xv.x * xv.x + xv.y * xv.y;
            s1b += xv.z + xv.w;  s2b += xv.z * xv.z + xv.w * xv.w;
        }
    }
    atomicAdd(&ls1[2 * c4],     s1a); atomicAdd(&ls2[2 * c4],     s2a);
    atomicAdd(&ls1[2 * c4 + 1], s1b); atomicAdd(&ls2[2 * c4 + 1], s2b);
    if (c4 == 0) atomicAdd(&lcnt, mc);
    __syncthreads();
    if (tid < 32) {
        atomicAdd(&stats[OFF_S1A + b * 32 + tid], ls1[tid]);
        atomicAdd(&stats[OFF_S2A + b * 32 + tid], ls2[tid]);
    }
    if (tid == 0) atomicAdd(&stats[OFF_CNT1 + b], lcnt);
}

// ------ Kernel 2: GN1 apply + SiLU + downsample -> h1b (bf16), xd -> xdb (bf16), dm ------
__global__ __launch_bounds__(256) void k2_down(const float* __restrict__ x,
                                               const int* __restrict__ mask,
                                               const float* __restrict__ gn1w,
                                               const float* __restrict__ gn1b,
                                               const float* __restrict__ stats,
                                               unsigned short* __restrict__ h1b,
                                               unsigned short* __restrict__ xdb,
                                               float* __restrict__ dm)
{
    int tid = threadIdx.x;
    int c  = tid & 63;
    int vl = tid >> 6;
    size_t ov = (size_t)blockIdx.x * 4 + vl;
    int b  = (int)(ov >> 15);
    int v2 = (int)(ov & 32767);
    int z = v2 >> 10, y = (v2 >> 5) & 31, xk = v2 & 31;

    int g = c >> 1;
    float ce   = fmaxf(stats[OFF_CNT1 + b] * 2.f, 1.f);
    float mean = stats[OFF_S1A + b * 32 + g] / ce;
    float var  = stats[OFF_S2A + b * 32 + g] / ce - mean * mean;
    float rinv = rsqrtf(var + 1e-5f);
    float a  = rinv * gn1w[c];
    float bc = gn1b[c] - mean * a;

    const int*   mb = mask + ((size_t)b << 18);
    const float* xb = x + (((size_t)b << 18) << 6);

    float hacc = 0.f, xacc = 0.f; int cnt = 0;
    #pragma unroll
    for (int dz = 0; dz < 2; ++dz)
    #pragma unroll
    for (int dy = 0; dy < 2; ++dy)
    #pragma unroll
    for (int dx = 0; dx < 2; ++dx) {
        int v1 = ((2 * z + dz) << 12) | ((2 * y + dy) << 6) | (2 * xk + dx);
        if (mb[v1]) {
            cnt++;
            float xv = xb[(size_t)v1 * 64 + c];
            xacc += xv;
            float yv = fmaf(xv, a, bc);
            hacc += yv / (1.f + expf(-yv));
        }
    }
    float inv = 1.f / fmaxf((float)cnt, 1.f);
    h1b[ov * 64 + c] = f2bf(hacc * inv);
    xdb[ov * 64 + c] = f2bf(xacc * inv);
    if (c == 0) dm[ov] = (cnt > 0) ? 1.f : 0.f;
}

// ---------------- MFMA implicit-GEMM conv 3x3x3 (+optional 1x1 skip taps) ----------------
// Block: 256 thr = 4 waves. Block tile: M=128 voxels (4 y-rows at one (b,z)), N=128.
// Wave: M=32 (1 y-row), N=128 -> acc[2][8] f32x4 (64 AGPR).
// Pipeline: A-frags prefetched 1 K-step ahead, B-slab 2 K-steps ahead (regs),
// LDS double-buffered. T4: raw barrier + lgkmcnt(0) only — global loads stay in
// flight across barriers; compiler emits counted vmcnt at use points.
template<int CIN, bool SKIP>
__global__ __launch_bounds__(256, 4) void conv3_mfma(
    const unsigned short* __restrict__ src,
    const unsigned short* __restrict__ sksrc,
    const unsigned short* __restrict__ wT,
    const float* __restrict__ bias,
    const float* __restrict__ bias2,
    const float* __restrict__ dm,
    float* __restrict__ outf,
    unsigned short* __restrict__ outb)
{
    constexpr int CS  = CIN / 32;
    constexpr int NKM = 27 * CS;
    constexpr int NK  = NKM + (SKIP ? 2 : 0);

    __shared__ short smem[2][4096];   // 2 x 8KB weight slabs

    const int tid  = threadIdx.x;
    const int lane = tid & 63;
    const int wv   = tid >> 6;
    // XCD-aware bijective swizzle: 1024 blocks, 8 XCDs, 128-block chunks
    const int orig = blockIdx.x;
    const int blk  = (orig & 7) * 128 + (orig >> 3);
    const int b    = blk >> 8;
    const int z    = (blk >> 3) & 31;
    const int yo   = blk & 7;
    const int y0   = yo * 4 + wv;      // this wave's y-row
    const int vb   = b * 32768;
    const int klo  = (lane >> 4) * 8;
    const int xl   = lane & 15;
    const int rlo  = (lane >> 4) * 4;

    const uint4* wT4 = (const uint4*)wT;
    uint4* sm4 = (uint4*)&smem[0][0];

    f32x4 acc[2][8];
    #pragma unroll
    for (int f = 0; f < 2; ++f)
        #pragma unroll
        for (int nb = 0; nb < 8; ++nb)
            acc[f][nb] = (f32x4){0.f, 0.f, 0.f, 0.f};

    // A-fragment loader for flattened K-step ks (uniform scalar decode)
    auto loadA = [&](int ks, bf16x8 af[2]) {
        const unsigned short* abase;
        int cinl, zz, dy1, dx1;
        if (SKIP && ks >= NKM) {
            abase = sksrc + (ks - NKM) * 32;
            cinl = 64; zz = z; dy1 = 0; dx1 = 0;
        } else {
            int tap = ks / CS, s = ks - tap * CS;       // CS is power of 2
            int dz = tap / 9, r = tap - dz * 9;
            int dy = r / 3,   dx = r - dy * 3;
            abase = src + s * 32;
            cinl = CIN; zz = z + dz - 1; dy1 = dy - 1; dx1 = dx - 1;
        }
        int yy = y0 + dy1;
        bool zyok = ((unsigned)zz < 32u) && ((unsigned)yy < 32u);
        #pragma unroll
        for (int f = 0; f < 2; ++f) {
            int xx = f * 16 + xl + dx1;
            bool ok = zyok && ((unsigned)xx < 32u);
            bf16x8 a = {};
            const unsigned short* ap =
                abase + (size_t)(vb + zz * 1024 + yy * 32 + xx) * (size_t)cinl + klo;
            if (ok) a = *(const bf16x8*)ap;
            af[f] = a;
        }
    };

    // ---- prologue: slab 0 -> LDS, A(0) -> regs, slab 1 -> regs ----
    {
        uint4 p0 = wT4[tid], p1 = wT4[tid + 256];
        sm4[tid] = p0; sm4[tid + 256] = p1;
    }
    bf16x8 afc[2];
    loadA(0, afc);
    uint4 qn0 = {}, qn1 = {};
    if (NK > 1) { qn0 = wT4[512 + tid]; qn1 = wT4[512 + 256 + tid]; }
    barrier_nodrain();

    int cur = 0;
    #pragma clang loop unroll(disable)
    for (int ks = 0; ks < NK; ++ks) {
        // issue-early: A for ks+1, B slab for ks+2
        bf16x8 afn[2] = {{}, {}};
        if (ks + 1 < NK) loadA(ks + 1, afn);
        uint4 r0 = {}, r1 = {};
        if (ks + 2 < NK) {
            r0 = wT4[(size_t)(ks + 2) * 512 + tid];
            r1 = wT4[(size_t)(ks + 2) * 512 + 256 + tid];
        }
        // MFMA phase: B from LDS[cur], A from regs (loaded last step)
        const int eoffb = cur * 4096 + ((lane >> 4) * 128 + xl) * 8;
        #pragma unroll
        for (int nb = 0; nb < 8; ++nb) {
            bf16x8 bfr = *(const bf16x8*)(&smem[0][0] + eoffb + nb * 128);
            acc[0][nb] = __builtin_amdgcn_mfma_f32_16x16x32_bf16(afc[0], bfr, acc[0][nb], 0, 0, 0);
            acc[1][nb] = __builtin_amdgcn_mfma_f32_16x16x32_bf16(afc[1], bfr, acc[1][nb], 0, 0, 0);
        }
        // write-late: slab ks+1 (loaded 1 step ago; counted vmcnt wait on qn)
        if (ks + 1 < NK) {
            sm4[(cur ^ 1) * 512 + tid] = qn0;
            sm4[(cur ^ 1) * 512 + 256 + tid] = qn1;
        }
        barrier_nodrain();
        afc[0] = afn[0]; afc[1] = afn[1];
        qn0 = r0; qn1 = r1;
        cur ^= 1;
    }

    // ---- epilogue ----
    float bv[8];
    #pragma unroll
    for (int nb = 0; nb < 8; ++nb) {
        int co = nb * 16 + xl;
        if constexpr (SKIP) bv[nb] = bias[co] + bias2[co];
        else                bv[nb] = bias[co];
    }
    #pragma unroll
    for (int f = 0; f < 2; ++f) {
        int xb2 = f * 16 + rlo;
        #pragma unroll
        for (int j = 0; j < 4; ++j) {
            int vox = vb + z * 1024 + y0 * 32 + xb2 + j;
            float dmx = dm[vox];
            #pragma unroll
            for (int nb = 0; nb < 8; ++nb) {
                float o = (acc[f][nb][j] + bv[nb]) * dmx;
                if constexpr (SKIP) outf[(size_t)vox * 128 + nb * 16 + xl] = o;
                else                outb[(size_t)vox * 128 + nb * 16 + xl] = f2bf(o);
            }
        }
    }
}

// ---------------- Kernel 4: GN2 stats over h2a (bf16) ----------------
__global__ __launch_bounds__(256) void k4_stats2(const unsigned short* __restrict__ h2a,
                                                 const float* __restrict__ dm,
                                                 float* __restrict__ stats)
{
    __shared__ float ls1[32], ls2[32];
    __shared__ float lcnt;
    int tid = threadIdx.x;
    if (tid < 32) { ls1[tid] = 0.f; ls2[tid] = 0.f; }
    if (tid == 0) lcnt = 0.f;
    __syncthreads();

    int b  = blockIdx.x & 3;
    int bb = blockIdx.x >> 2;
    int g  = tid & 31;
    int vl = tid >> 5;

    const unsigned short* hb = h2a + ((size_t)b * V2) * C2;
    const float* dmb = dm + (size_t)b * V2;

    float s1 = 0.f, s2 = 0.f, mc = 0.f;
    for (int ch = bb; ch < V2 / 8; ch += 1024) {
        int v = ch * 8 + vl;
        float m = dmb[v];
        if (g == 0) mc += m;
        if (m != 0.f) {
            ushort4 hv = *(const ushort4*)(hb + (size_t)v * C2 + g * 4);
            float h0 = bf2f(hv.x), h1 = bf2f(hv.y), h2 = bf2f(hv.z), h3 = bf2f(hv.w);
            s1 += h0 + h1 + h2 + h3;
            s2 += h0 * h0 + h1 * h1 + h2 * h2 + h3 * h3;
        }
    }
    atomicAdd(&ls1[g], s1); atomicAdd(&ls2[g], s2);
    if (g == 0) atomicAdd(&lcnt, mc);
    __syncthreads();
    if (tid < 32) {
        atomicAdd(&stats[OFF_S1B + b * 32 + tid], ls1[tid]);
        atomicAdd(&stats[OFF_S2B + b * 32 + tid], ls2[tid]);
    }
    if (tid == 0) atomicAdd(&stats[OFF_CNT2 + b], lcnt);
}

// ---------------- Kernel 5: GN2 apply + SiLU -> h2b (bf16) ----------------
__global__ __launch_bounds__(256) void k5_gn2(const unsigned short* __restrict__ h2a,
                                              unsigned short* __restrict__ h2b,
                                              const float* __restrict__ stats,
                                              const float* __restrict__ dm,
                                              const float* __restrict__ gn2w,
                                              const float* __restrict__ gn2b)
{
    int idx = blockIdx.x * 256 + threadIdx.x;   // group-quad index
    int v = idx >> 5, g = idx & 31;
    int b = v >> 15;
    float ce   = fmaxf(stats[OFF_CNT2 + b] * 4.f, 1.f);
    float mean = stats[OFF_S1B + b * 32 + g] / ce;
    float var  = stats[OFF_S2B + b * 32 + g] / ce - mean * mean;
    float rinv = rsqrtf(var + 1e-5f);
    float dmv  = dm[v];
    ushort4 hv = *(const ushort4*)(h2a + (size_t)idx * 4);
    float4 gw = *(const float4*)(gn2w + g * 4);
    float4 gb = *(const float4*)(gn2b + g * 4);
    float a, t;
    ushort4 o;
    a = rinv * gw.x; t = (fmaf(bf2f(hv.x), a, gb.x - mean * a)) * dmv; o.x = f2bf(t / (1.f + expf(-t)));
    a = rinv * gw.y; t = (fmaf(bf2f(hv.y), a, gb.y - mean * a)) * dmv; o.y = f2bf(t / (1.f + expf(-t)));
    a = rinv * gw.z; t = (fmaf(bf2f(hv.z), a, gb.z - mean * a)) * dmv; o.z = f2bf(t / (1.f + expf(-t)));
    a = rinv * gw.w; t = (fmaf(bf2f(hv.w), a, gb.w - mean * a)) * dmv; o.w = f2bf(t / (1.f + expf(-t)));
    *(ushort4*)(h2b + (size_t)idx * 4) = o;
}

extern "C" void kernel_launch(void* const* d_in, const int* in_sizes, int n_in,
                              void* d_out, int out_size, void* d_ws, size_t ws_size,
                              hipStream_t stream)
{
    const float* x     = (const float*)d_in[0];
    const int*   mask  = (const int*)d_in[1];
    const float* gn1w  = (const float*)d_in[2];
    const float* gn1b  = (const float*)d_in[3];
    const float* w1    = (const float*)d_in[4];
    const float* b1    = (const float*)d_in[5];
    const float* gn2w  = (const float*)d_in[6];
    const float* gn2b  = (const float*)d_in[7];
    const float* w2    = (const float*)d_in[8];
    const float* b2    = (const float*)d_in[9];
    const float* wskip = (const float*)d_in[10];
    const float* bskip = (const float*)d_in[11];
    float* out = (float*)d_out;

    char* wsb = (char*)d_ws;
    float*          stats = (float*)wsb;                          // 520 f32
    float*          dm    = (float*)(wsb + 4096);                 // 131072 f32
    unsigned short* h1b   = (unsigned short*)(wsb + 528384);      // 131072*64 bf16
    unsigned short* xdb   = (unsigned short*)(wsb + 17305600);    // 131072*64 bf16
    unsigned short* h2a   = (unsigned short*)(wsb + 34082816);    // 131072*128 bf16
    unsigned short* h2b   = (unsigned short*)(wsb + 67637248);    // 131072*128 bf16
    unsigned short* w1t   = (unsigned short*)(wsb + 101191680);   // 54*4096 bf16
    unsigned short* w2t   = (unsigned short*)(wsb + 101634048);   // 110*4096 bf16

    hipMemsetAsync(stats, 0, 520 * sizeof(float), stream);

    hipLaunchKernelGGL(k0_wprep, dim3(2624), dim3(256), 0, stream, w1, w2, wskip, w1t, w2t);
    hipLaunchKernelGGL(k1_stats1, dim3(4096), dim3(256), 0, stream, x, mask, stats);
    hipLaunchKernelGGL(k2_down, dim3(32768), dim3(256), 0, stream,
                       x, mask, gn1w, gn1b, stats, h1b, xdb, dm);
    hipLaunchKernelGGL((conv3_mfma<64, false>), dim3(1024), dim3(256), 0, stream,
                       h1b, (const unsigned short*)nullptr, w1t, b1, (const float*)nullptr,
                       dm, (float*)nullptr, h2a);
    hipLaunchKernelGGL(k4_stats2, dim3(4096), dim3(256), 0, stream, h2a, dm, stats);
    hipLaunchKernelGGL(k5_gn2, dim3(16384), dim3(256), 0, stream, h2a, h2b, stats, dm, gn2w, gn2b);
    hipLaunchKernelGGL((conv3_mfma<128, true>), dim3(1024), dim3(256), 0, stream,
                       h2b, xdb, w2t, b2, bskip, dm, out, (unsigned short*)nullptr);
}

// Round 9
// 450.561 us; speedup vs baseline: 1.6474x; 1.0444x over previous
//
#include <hip/hip_runtime.h>
#include <cstdint>
#include <cstddef>

#define B_ 4
#define V1 262144   // 64^3
#define C1 64
#define V2 32768    // 32^3
#define C2 128
#define TOTV 131072
#define P_ 34
#define P2_ 1156
#define P3_ 39304
#define SBSTRIDE ((size_t)4 * P3_)   // slice stride in voxel-records ([s][b] layout)

// stats layout (float indices within stats buffer)
#define OFF_S1A 0
#define OFF_S2A 128
#define OFF_CNT1 256
#define OFF_S1B 260
#define OFF_S2B 388
#define OFF_CNT2 516

typedef __bf16 bf16x8 __attribute__((ext_vector_type(8)));
typedef float f32x4 __attribute__((ext_vector_type(4)));

__device__ __forceinline__ float bf2f(unsigned short u) {
    return __builtin_bit_cast(float, (unsigned)u << 16);
}
__device__ __forceinline__ unsigned short f2bf(float f) {
    unsigned u = __builtin_bit_cast(unsigned, f);
    u += 0x7fffu + ((u >> 16) & 1u);     // RTNE
    return (unsigned short)(u >> 16);
}

// T4: barrier WITHOUT vmcnt drain — LDS ordering only.
__device__ __forceinline__ void barrier_nodrain() {
    asm volatile("s_waitcnt lgkmcnt(0)" ::: "memory");
    __builtin_amdgcn_s_barrier();
}

// byte offset of main-step ks's A-base (lane-independent part), CS = 1<<csh
__device__ __forceinline__ int a_ofs(int ks, int csh) {
    int s = ks & ((1 << csh) - 1), tap = ks >> csh;
    int dz = tap / 9, r = tap % 9, dy = r / 3, dx = r % 3;
    return s * (int)(SBSTRIDE * 64) + (dz * P2_ + dy * P_ + dx) * 64;
}

// ---------------- Kernel 0: weight prep + A-delta tables ----------------
// Slabs tap-major: slab = t*CS + s. Within slab: [q4][n128][j8], k=q*8+j, n=co.
__global__ __launch_bounds__(256) void k0_wprep(const float* __restrict__ w1,
                                                const float* __restrict__ w2,
                                                const float* __restrict__ wskip,
                                                unsigned short* __restrict__ w1t,
                                                unsigned short* __restrict__ w2t,
                                                int* __restrict__ d1,
                                                int* __restrict__ d2)
{
    int i = blockIdx.x * 256 + threadIdx.x;
    if (blockIdx.x == 0) {
        int t = threadIdx.x;
        if (t < 54)               d1[t] = (t + 1 < 54)  ? a_ofs(t + 1, 1) - a_ofs(t, 1) : 0;
        if (t >= 64 && t < 172) { int j = t - 64;
                                  d2[j] = (j + 1 < 108) ? a_ofs(j + 1, 2) - a_ofs(j, 2) : 0; }
    }
    if (i < 54 * 4096) {
        int slab = i >> 12, r = i & 4095;
        int q = r >> 10, n = (r >> 3) & 127, j = r & 7;
        int t = slab >> 1, s = slab & 1;
        int ci = s * 32 + q * 8 + j;
        w1t[i] = f2bf(w1[((size_t)t * 64 + ci) * 128 + n]);
    }
    int i2 = i - 54 * 4096;
    if (i2 >= 0 && i2 < 110 * 4096) {
        int slab = i2 >> 12, r = i2 & 4095;
        int q = r >> 10, n = (r >> 3) & 127, j = r & 7;
        float v;
        if (slab < 108) {
            int t = slab >> 2, s = slab & 3;
            int ci = s * 32 + q * 8 + j;
            v = w2[((size_t)t * 128 + ci) * 128 + n];
        } else {
            int ci = (slab - 108) * 32 + q * 8 + j;
            v = wskip[(size_t)ci * 128 + n];
        }
        w2t[i2] = f2bf(v);
    }
}

// ---------------- Kernel Z: zero padded-buffer borders (h1p: 8 sb, h2p: 16 sb) ----------------
__global__ __launch_bounds__(256) void kz_border(unsigned short* __restrict__ h1p,
                                                 unsigned short* __restrict__ h2p)
{
    int i = blockIdx.x * 256 + threadIdx.x;      // one voxel-record per thread
    if (i >= 24 * P3_) return;
    int sb = i / P3_, vox = i % P3_;
    int vz = vox / P2_, r = vox % P2_, vy = r / P_, vx = r % P_;
    bool border = (vz == 0) | (vz == 33) | (vy == 0) | (vy == 33) | (vx == 0) | (vx == 33);
    if (!border) return;
    unsigned short* base = (sb < 8) ? (h1p + (size_t)sb * P3_ * 32 + (size_t)vox * 32)
                                    : (h2p + (size_t)(sb - 8) * P3_ * 32 + (size_t)vox * 32);
    uint4 z = {0, 0, 0, 0};
    uint4* b4 = (uint4*)base;
    b4[0] = z; b4[1] = z; b4[2] = z; b4[3] = z;
}

// ---------------- Kernel 1: GN1 stats ----------------
__global__ __launch_bounds__(256) void k1_stats1(const float* __restrict__ x,
                                                 const int* __restrict__ mask,
                                                 float* __restrict__ stats)
{
    __shared__ float ls1[32], ls2[32];
    __shared__ float lcnt;
    int tid = threadIdx.x;
    if (tid < 32) { ls1[tid] = 0.f; ls2[tid] = 0.f; }
    if (tid == 0) lcnt = 0.f;
    __syncthreads();

    int b  = blockIdx.x & 3;
    int bb = blockIdx.x >> 2;
    int c4 = tid & 15;
    int vl = tid >> 4;

    const float* xb = x + ((size_t)b * V1) * C1;
    const int*   mb = mask + (size_t)b * V1;

    float s1a = 0.f, s2a = 0.f, s1b = 0.f, s2b = 0.f, mc = 0.f;
    for (int ch = bb; ch < V1 / 16; ch += 1024) {
        int v = ch * 16 + vl;
        int m = mb[v];
        if (c4 == 0) mc += (float)m;
        if (m) {
            float4 xv = *(const float4*)(xb + (size_t)v * C1 + c4 * 4);
            s1a += xv.x + xv.y;  s2a += xv.x * xv.x + xv.y * xv.y;
            s1b += xv.z + xv.w;  s2b += xv.z * xv.z + xv.w * xv.w;
        }
    }
    atomicAdd(&ls1[2 * c4],     s1a); atomicAdd(&ls2[2 * c4],     s2a);
    atomicAdd(&ls1[2 * c4 + 1], s1b); atomicAdd(&ls2[2 * c4 + 1], s2b);
    if (c4 == 0) atomicAdd(&lcnt, mc);
    __syncthreads();
    if (tid < 32) {
        atomicAdd(&stats[OFF_S1A + b * 32 + tid], ls1[tid]);
        atomicAdd(&stats[OFF_S2A + b * 32 + tid], ls2[tid]);
    }
    if (tid == 0) atomicAdd(&stats[OFF_CNT1 + b], lcnt);
}

// ------ Kernel 2: GN1 apply + SiLU + downsample -> h1p (padded sliced), xdb (flat), dm ------
__global__ __launch_bounds__(256) void k2_down(const float* __restrict__ x,
                                               const int* __restrict__ mask,
                                               const float* __restrict__ gn1w,
                                               const float* __restrict__ gn1b,
                                               const float* __restrict__ stats,
                                               unsigned short* __restrict__ h1p,
                                               unsigned short* __restrict__ xdb,
                                               float* __restrict__ dm)
{
    int tid = threadIdx.x;
    int c  = tid & 63;
    int vl = tid >> 6;
    size_t ov = (size_t)blockIdx.x * 4 + vl;
    int b  = (int)(ov >> 15);
    int v2 = (int)(ov & 32767);
    int z = v2 >> 10, y = (v2 >> 5) & 31, xk = v2 & 31;

    int g = c >> 1;
    float ce   = fmaxf(stats[OFF_CNT1 + b] * 2.f, 1.f);
    float mean = stats[OFF_S1A + b * 32 + g] / ce;
    float var  = stats[OFF_S2A + b * 32 + g] / ce - mean * mean;
    float rinv = rsqrtf(var + 1e-5f);
    float a  = rinv * gn1w[c];
    float bc = gn1b[c] - mean * a;

    const int*   mb = mask + ((size_t)b << 18);
    const float* xb = x + (((size_t)b << 18) << 6);

    float hacc = 0.f, xacc = 0.f; int cnt = 0;
    #pragma unroll
    for (int dz = 0; dz < 2; ++dz)
    #pragma unroll
    for (int dy = 0; dy < 2; ++dy)
    #pragma unroll
    for (int dx = 0; dx < 2; ++dx) {
        int v1 = ((2 * z + dz) << 12) | ((2 * y + dy) << 6) | (2 * xk + dx);
        if (mb[v1]) {
            cnt++;
            float xv = xb[(size_t)v1 * 64 + c];
            xacc += xv;
            float yv = fmaf(xv, a, bc);
            hacc += yv / (1.f + expf(-yv));
        }
    }
    float inv = 1.f / fmaxf((float)cnt, 1.f);
    int pvox = (z + 1) * P2_ + (y + 1) * P_ + (xk + 1);
    size_t so = ((size_t)(c >> 5) * SBSTRIDE + (size_t)b * P3_ + pvox) * 32 + (c & 31);
    h1p[so] = f2bf(hacc * inv);
    xdb[ov * 64 + c] = f2bf(xacc * inv);
    if (c == 0) dm[ov] = (cnt > 0) ? 1.f : 0.f;
}

// ---------------- MFMA implicit-GEMM conv 3x3x3 (+optional 1x1 skip taps) ----------------
// Block: 256 thr = 4 waves. Block tile: M=128 voxels (4 y-rows at one (b,z)), N=128.
// Wave: M=32 (1 y-row), N=128 -> acc[2][8] f32x4 (64 AGPR).
// Padded channel-sliced A source -> unconditional loads; A addr walks via scalar
// delta table (no decode/predication VALU). B-slab LDS dbuf, W 2-ahead, A 1-ahead.
template<int CIN, bool SKIP>
__global__ __launch_bounds__(256, 4) void conv3_mfma(
    const unsigned short* __restrict__ srcP,   // padded [CS][4][34^3][32]
    const unsigned short* __restrict__ sksrc,  // flat [TOTV][64] (skip) or null
    const unsigned short* __restrict__ wT,
    const int* __restrict__ tblA,
    const float* __restrict__ bias,
    const float* __restrict__ bias2,
    const float* __restrict__ dm,
    float* __restrict__ outf,
    unsigned short* __restrict__ outb)
{
    constexpr int CS  = CIN / 32;
    constexpr int NKM = 27 * CS;
    constexpr int NK  = NKM + (SKIP ? 2 : 0);

    __shared__ short smem[2][4096];   // 2 x 8KB weight slabs

    const int tid  = threadIdx.x;
    const int lane = tid & 63;
    const int wv   = tid >> 6;
    // XCD-aware bijective swizzle: 1024 blocks, 8 XCDs, 128-block chunks
    const int orig = blockIdx.x;
    const int blk  = (orig & 7) * 128 + (orig >> 3);
    const int b    = blk >> 8;
    const int z    = (blk >> 3) & 31;
    const int yo   = blk & 7;
    const int y0   = yo * 4 + wv;      // this wave's y-row
    const int vb   = b * 32768;
    const int klo  = (lane >> 4) * 8;
    const int xl   = lane & 15;
    const int rlo  = (lane >> 4) * 4;

    const uint4* wT4 = (const uint4*)wT;
    uint4* sm4 = (uint4*)&smem[0][0];

    f32x4 acc[2][8];
    #pragma unroll
    for (int f = 0; f < 2; ++f)
        #pragma unroll
        for (int nb = 0; nb < 8; ++nb)
            acc[f][nb] = (f32x4){0.f, 0.f, 0.f, 0.f};

    // per-lane A pointer at step 0 (tap dz=dy=dx=0, s=0): padded coords (z, y0, xl)
    const char* pA = (const char*)srcP +
        (((size_t)b * P3_ + (size_t)(z * P2_ + y0 * P_ + xl)) * 32 + klo) * 2;

    // skip-phase A loader (flat xdb, center tap, always in bounds)
    auto loadSkip = [&](int ss, bf16x8 af[2]) {
        const unsigned short* abase = sksrc + ss * 32;
        #pragma unroll
        for (int f = 0; f < 2; ++f) {
            int xx = f * 16 + xl;
            af[f] = *(const bf16x8*)(abase +
                     (size_t)(vb + z * 1024 + y0 * 32 + xx) * 64 + klo);
        }
    };

    // ---- prologue: slab 0 -> LDS, A(0) -> regs, slab 1 -> regs ----
    {
        uint4 p0 = wT4[tid], p1 = wT4[tid + 256];
        sm4[tid] = p0; sm4[tid + 256] = p1;
    }
    bf16x8 afc[2];
    afc[0] = *(const bf16x8*)pA;
    afc[1] = *(const bf16x8*)(pA + 1024);
    pA += tblA[0];
    const uint4* wRun = wT4 + 1024 + tid;   // slab 2 base (+tid)
    uint4 qn0 = {}, qn1 = {};
    if (NK > 1) { qn0 = wT4[512 + tid]; qn1 = wT4[512 + 256 + tid]; }
    barrier_nodrain();

    int cur = 0;
    #pragma unroll 2
    for (int ks = 0; ks < NK; ++ks) {
        // issue-early: A for ks+1 (pointer walk), W slab for ks+2
        bf16x8 afn[2] = {{}, {}};
        if (ks + 1 < NKM) {
            afn[0] = *(const bf16x8*)pA;
            afn[1] = *(const bf16x8*)(pA + 1024);
            pA += tblA[ks + 1];
        } else if (SKIP && ks + 1 < NK) {
            loadSkip(ks + 1 - NKM, afn);
        }
        uint4 r0 = {}, r1 = {};
        if (ks + 2 < NK) { r0 = wRun[0]; r1 = wRun[256]; }
        wRun += 512;
        // MFMA phase: B from LDS[cur], A from regs (loaded last step)
        const int eoffb = cur * 4096 + ((lane >> 4) * 128 + xl) * 8;
        #pragma unroll
        for (int nb = 0; nb < 8; ++nb) {
            bf16x8 bfr = *(const bf16x8*)(&smem[0][0] + eoffb + nb * 128);
            acc[0][nb] = __builtin_amdgcn_mfma_f32_16x16x32_bf16(afc[0], bfr, acc[0][nb], 0, 0, 0);
            acc[1][nb] = __builtin_amdgcn_mfma_f32_16x16x32_bf16(afc[1], bfr, acc[1][nb], 0, 0, 0);
        }
        // write-late: slab ks+1 (loaded 1 step ago)
        if (ks + 1 < NK) {
            sm4[(cur ^ 1) * 512 + tid] = qn0;
            sm4[(cur ^ 1) * 512 + 256 + tid] = qn1;
        }
        barrier_nodrain();
        afc[0] = afn[0]; afc[1] = afn[1];
        qn0 = r0; qn1 = r1;
        cur ^= 1;
    }

    // ---- epilogue ----
    float bv[8];
    #pragma unroll
    for (int nb = 0; nb < 8; ++nb) {
        int co = nb * 16 + xl;
        if constexpr (SKIP) bv[nb] = bias[co] + bias2[co];
        else                bv[nb] = bias[co];
    }
    #pragma unroll
    for (int f = 0; f < 2; ++f) {
        int xb2 = f * 16 + rlo;
        #pragma unroll
        for (int j = 0; j < 4; ++j) {
            int vox = vb + z * 1024 + y0 * 32 + xb2 + j;
            float dmx = dm[vox];
            #pragma unroll
            for (int nb = 0; nb < 8; ++nb) {
                float o = (acc[f][nb][j] + bv[nb]) * dmx;
                if constexpr (SKIP) outf[(size_t)vox * 128 + nb * 16 + xl] = o;
                else                outb[(size_t)vox * 128 + nb * 16 + xl] = f2bf(o);
            }
        }
    }
}

// ---------------- Kernel 4: GN2 stats over h2a (flat bf16) ----------------
__global__ __launch_bounds__(256) void k4_stats2(const unsigned short* __restrict__ h2a,
                                                 const float* __restrict__ dm,
                                                 float* __restrict__ stats)
{
    __shared__ float ls1[32], ls2[32];
    __shared__ float lcnt;
    int tid = threadIdx.x;
    if (tid < 32) { ls1[tid] = 0.f; ls2[tid] = 0.f; }
    if (tid == 0) lcnt = 0.f;
    __syncthreads();

    int b  = blockIdx.x & 3;
    int bb = blockIdx.x >> 2;
    int g  = tid & 31;
    int vl = tid >> 5;

    const unsigned short* hb = h2a + ((size_t)b * V2) * C2;
    const float* dmb = dm + (size_t)b * V2;

    float s1 = 0.f, s2 = 0.f, mc = 0.f;
    for (int ch = bb; ch < V2 / 8; ch += 1024) {
        int v = ch * 8 + vl;
        float m = dmb[v];
        if (g == 0) mc += m;
        if (m != 0.f) {
            ushort4 hv = *(const ushort4*)(hb + (size_t)v * C2 + g * 4);
            float h0 = bf2f(hv.x), h1 = bf2f(hv.y), h2 = bf2f(hv.z), h3 = bf2f(hv.w);
            s1 += h0 + h1 + h2 + h3;
            s2 += h0 * h0 + h1 * h1 + h2 * h2 + h3 * h3;
        }
    }
    atomicAdd(&ls1[g], s1); atomicAdd(&ls2[g], s2);
    if (g == 0) atomicAdd(&lcnt, mc);
    __syncthreads();
    if (tid < 32) {
        atomicAdd(&stats[OFF_S1B + b * 32 + tid], ls1[tid]);
        atomicAdd(&stats[OFF_S2B + b * 32 + tid], ls2[tid]);
    }
    if (tid == 0) atomicAdd(&stats[OFF_CNT2 + b], lcnt);
}

// ---------------- Kernel 5: GN2 apply + SiLU -> h2p (padded sliced bf16) ----------------
__global__ __launch_bounds__(256) void k5_gn2(const unsigned short* __restrict__ h2a,
                                              unsigned short* __restrict__ h2p,
                                              const float* __restrict__ stats,
                                              const float* __restrict__ dm,
                                              const float* __restrict__ gn2w,
                                              const float* __restrict__ gn2b)
{
    int idx = blockIdx.x * 256 + threadIdx.x;   // group-quad index
    int v = idx >> 5, g = idx & 31;
    int b = v >> 15;
    int v2 = v & 32767;
    float ce   = fmaxf(stats[OFF_CNT2 + b] * 4.f, 1.f);
    float mean = stats[OFF_S1B + b * 32 + g] / ce;
    float var  = stats[OFF_S2B + b * 32 + g] / ce - mean * mean;
    float rinv = rsqrtf(var + 1e-5f);
    float dmv  = dm[v];
    ushort4 hv = *(const ushort4*)(h2a + (size_t)idx * 4);
    float4 gw = *(const float4*)(gn2w + g * 4);
    float4 gb = *(const float4*)(gn2b + g * 4);
    float a, t;
    ushort4 o;
    a = rinv * gw.x; t = (fmaf(bf2f(hv.x), a, gb.x - mean * a)) * dmv; o.x = f2bf(t / (1.f + expf(-t)));
    a = rinv * gw.y; t = (fmaf(bf2f(hv.y), a, gb.y - mean * a)) * dmv; o.y = f2bf(t / (1.f + expf(-t)));
    a = rinv * gw.z; t = (fmaf(bf2f(hv.z), a, gb.z - mean * a)) * dmv; o.z = f2bf(t / (1.f + expf(-t)));
    a = rinv * gw.w; t = (fmaf(bf2f(hv.w), a, gb.w - mean * a)) * dmv; o.w = f2bf(t / (1.f + expf(-t)));
    int zz = v2 >> 10, yy = (v2 >> 5) & 31, xx = v2 & 31;
    int pvox = (zz + 1) * P2_ + (yy + 1) * P_ + (xx + 1);
    size_t so = ((size_t)(g >> 3) * SBSTRIDE + (size_t)b * P3_ + pvox) * 32 + (g & 7) * 4;
    *(ushort4*)(h2p + so) = o;
}

extern "C" void kernel_launch(void* const* d_in, const int* in_sizes, int n_in,
                              void* d_out, int out_size, void* d_ws, size_t ws_size,
                              hipStream_t stream)
{
    const float* x     = (const float*)d_in[0];
    const int*   mask  = (const int*)d_in[1];
    const float* gn1w  = (const float*)d_in[2];
    const float* gn1b  = (const float*)d_in[3];
    const float* w1    = (const float*)d_in[4];
    const float* b1    = (const float*)d_in[5];
    const float* gn2w  = (const float*)d_in[6];
    const float* gn2b  = (const float*)d_in[7];
    const float* w2    = (const float*)d_in[8];
    const float* b2    = (const float*)d_in[9];
    const float* wskip = (const float*)d_in[10];
    const float* bskip = (const float*)d_in[11];
    float* out = (float*)d_out;

    char* wsb = (char*)d_ws;
    float*          stats = (float*)wsb;                           // 520 f32
    float*          dm    = (float*)(wsb + 4096);                  // 131072 f32
    unsigned short* h1p   = (unsigned short*)(wsb + 528384);       // 8 sb x 34^3 x 32
    unsigned short* xdb   = (unsigned short*)(wsb + 20652032);     // [TOTV][64]
    unsigned short* h2a   = (unsigned short*)(wsb + 37429248);     // [TOTV][128]
    unsigned short* h2p   = (unsigned short*)(wsb + 70983680);     // 16 sb x 34^3 x 32
    unsigned short* w1t   = (unsigned short*)(wsb + 111230976);    // 54*4096
    unsigned short* w2t   = (unsigned short*)(wsb + 111673344);    // 110*4096
    int*            d1    = (int*)(wsb + 112574464);               // 54 ints
    int*            d2    = (int*)(wsb + 112574720);               // 108 ints

    hipMemsetAsync(stats, 0, 520 * sizeof(float), stream);

    hipLaunchKernelGGL(k0_wprep, dim3(2624), dim3(256), 0, stream, w1, w2, wskip, w1t, w2t, d1, d2);
    hipLaunchKernelGGL(kz_border, dim3((24 * P3_ + 255) / 256), dim3(256), 0, stream, h1p, h2p);
    hipLaunchKernelGGL(k1_stats1, dim3(4096), dim3(256), 0, stream, x, mask, stats);
    hipLaunchKernelGGL(k2_down, dim3(32768), dim3(256), 0, stream,
                       x, mask, gn1w, gn1b, stats, h1p, xdb, dm);
    hipLaunchKernelGGL((conv3_mfma<64, false>), dim3(1024), dim3(256), 0, stream,
                       h1p, (const unsigned short*)nullptr, w1t, d1, b1, (const float*)nullptr,
                       dm, (float*)nullptr, h2a);
    hipLaunchKernelGGL(k4_stats2, dim3(4096), dim3(256), 0, stream, h2a, dm, stats);
    hipLaunchKernelGGL(k5_gn2, dim3(16384), dim3(256), 0, stream, h2a, h2p, stats, dm, gn2w, gn2b);
    hipLaunchKernelGGL((conv3_mfma<128, true>), dim3(1024), dim3(256), 0, stream,
                       h2p, xdb, w2t, d2, b2, bskip, dm, out, (unsigned short*)nullptr);
}

// Round 11
// 442.125 us; speedup vs baseline: 1.6789x; 1.0191x over previous
//
#include <hip/hip_runtime.h>
#include <cstdint>
#include <cstddef>

#define B_ 4
#define V1 262144   // 64^3
#define C1 64
#define V2 32768    // 32^3
#define C2 128
#define TOTV 131072
#define P_ 34
#define P2_ 1156
#define P3_ 39304
#define SBSTRIDE ((size_t)4 * P3_)   // slice stride in voxel-records ([s][b] layout)

// stats layout (float indices within stats buffer)
#define OFF_S1A 0
#define OFF_S2A 128
#define OFF_CNT1 256
#define OFF_S1B 260
#define OFF_S2B 388
#define OFF_CNT2 516

typedef __bf16 bf16x8 __attribute__((ext_vector_type(8)));
typedef float f32x4 __attribute__((ext_vector_type(4)));

__device__ __forceinline__ float bf2f(unsigned short u) {
    return __builtin_bit_cast(float, (unsigned)u << 16);
}
__device__ __forceinline__ unsigned short f2bf(float f) {
    unsigned u = __builtin_bit_cast(unsigned, f);
    u += 0x7fffu + ((u >> 16) & 1u);     // RTNE
    return (unsigned short)(u >> 16);
}

// byte offset of main-step ks's A-base (lane-independent part), CS = 1<<csh
__device__ __forceinline__ int a_ofs(int ks, int csh) {
    int s = ks & ((1 << csh) - 1), tap = ks >> csh;
    int dz = tap / 9, r = tap % 9, dy = r / 3, dx = r % 3;
    return s * (int)(SBSTRIDE * 64) + (dz * P2_ + dy * P_ + dx) * 64;
}

// ---------------- Kernel 0: weight prep + A-delta tables ----------------
// Slabs tap-major: slab = t*CS + s. Within slab: [q4][n128][j8], k=q*8+j, n=co.
__global__ __launch_bounds__(256) void k0_wprep(const float* __restrict__ w1,
                                                const float* __restrict__ w2,
                                                const float* __restrict__ wskip,
                                                unsigned short* __restrict__ w1t,
                                                unsigned short* __restrict__ w2t,
                                                int* __restrict__ d1,
                                                int* __restrict__ d2)
{
    int i = blockIdx.x * 256 + threadIdx.x;
    if (blockIdx.x == 0) {
        int t = threadIdx.x;
        if (t < 54)               d1[t] = (t + 1 < 54)  ? a_ofs(t + 1, 1) - a_ofs(t, 1) : 0;
        if (t >= 64 && t < 172) { int j = t - 64;
                                  d2[j] = (j + 1 < 108) ? a_ofs(j + 1, 2) - a_ofs(j, 2) : 0; }
    }
    if (i < 54 * 4096) {
        int slab = i >> 12, r = i & 4095;
        int q = r >> 10, n = (r >> 3) & 127, j = r & 7;
        int t = slab >> 1, s = slab & 1;
        int ci = s * 32 + q * 8 + j;
        w1t[i] = f2bf(w1[((size_t)t * 64 + ci) * 128 + n]);
    }
    int i2 = i - 54 * 4096;
    if (i2 >= 0 && i2 < 110 * 4096) {
        int slab = i2 >> 12, r = i2 & 4095;
        int q = r >> 10, n = (r >> 3) & 127, j = r & 7;
        float v;
        if (slab < 108) {
            int t = slab >> 2, s = slab & 3;
            int ci = s * 32 + q * 8 + j;
            v = w2[((size_t)t * 128 + ci) * 128 + n];
        } else {
            int ci = (slab - 108) * 32 + q * 8 + j;
            v = wskip[(size_t)ci * 128 + n];
        }
        w2t[i2] = f2bf(v);
    }
}

// ---------------- Kernel Z: zero padded-buffer borders (h1p: 8 sb, h2p: 16 sb) ----------------
__global__ __launch_bounds__(256) void kz_border(unsigned short* __restrict__ h1p,
                                                 unsigned short* __restrict__ h2p)
{
    int i = blockIdx.x * 256 + threadIdx.x;      // one voxel-record per thread
    if (i >= 24 * P3_) return;
    int sb = i / P3_, vox = i % P3_;
    int vz = vox / P2_, r = vox % P2_, vy = r / P_, vx = r % P_;
    bool border = (vz == 0) | (vz == 33) | (vy == 0) | (vy == 33) | (vx == 0) | (vx == 33);
    if (!border) return;
    unsigned short* base = (sb < 8) ? (h1p + (size_t)sb * P3_ * 32 + (size_t)vox * 32)
                                    : (h2p + (size_t)(sb - 8) * P3_ * 32 + (size_t)vox * 32);
    uint4 z = {0, 0, 0, 0};
    uint4* b4 = (uint4*)base;
    b4[0] = z; b4[1] = z; b4[2] = z; b4[3] = z;
}

// ---------------- Kernel 1: GN1 stats ----------------
__global__ __launch_bounds__(256) void k1_stats1(const float* __restrict__ x,
                                                 const int* __restrict__ mask,
                                                 float* __restrict__ stats)
{
    __shared__ float ls1[32], ls2[32];
    __shared__ float lcnt;
    int tid = threadIdx.x;
    if (tid < 32) { ls1[tid] = 0.f; ls2[tid] = 0.f; }
    if (tid == 0) lcnt = 0.f;
    __syncthreads();

    int b  = blockIdx.x & 3;
    int bb = blockIdx.x >> 2;
    int c4 = tid & 15;
    int vl = tid >> 4;

    const float* xb = x + ((size_t)b * V1) * C1;
    const int*   mb = mask + (size_t)b * V1;

    float s1a = 0.f, s2a = 0.f, s1b = 0.f, s2b = 0.f, mc = 0.f;
    for (int ch = bb; ch < V1 / 16; ch += 1024) {
        int v = ch * 16 + vl;
        int m = mb[v];
        if (c4 == 0) mc += (float)m;
        if (m) {
            float4 xv = *(const float4*)(xb + (size_t)v * C1 + c4 * 4);
            s1a += xv.x + xv.y;  s2a += xv.x * xv.x + xv.y * xv.y;
            s1b += xv.z + xv.w;  s2b += xv.z * xv.z + xv.w * xv.w;
        }
    }
    atomicAdd(&ls1[2 * c4],     s1a); atomicAdd(&ls2[2 * c4],     s2a);
    atomicAdd(&ls1[2 * c4 + 1], s1b); atomicAdd(&ls2[2 * c4 + 1], s2b);
    if (c4 == 0) atomicAdd(&lcnt, mc);
    __syncthreads();
    if (tid < 32) {
        atomicAdd(&stats[OFF_S1A + b * 32 + tid], ls1[tid]);
        atomicAdd(&stats[OFF_S2A + b * 32 + tid], ls2[tid]);
    }
    if (tid == 0) atomicAdd(&stats[OFF_CNT1 + b], lcnt);
}

// ------ Kernel 2: GN1 apply + SiLU + downsample -> h1p (padded sliced), xdb (flat), dm ------
__global__ __launch_bounds__(256) void k2_down(const float* __restrict__ x,
                                               const int* __restrict__ mask,
                                               const float* __restrict__ gn1w,
                                               const float* __restrict__ gn1b,
                                               const float* __restrict__ stats,
                                               unsigned short* __restrict__ h1p,
                                               unsigned short* __restrict__ xdb,
                                               float* __restrict__ dm)
{
    int tid = threadIdx.x;
    int c  = tid & 63;
    int vl = tid >> 6;
    size_t ov = (size_t)blockIdx.x * 4 + vl;
    int b  = (int)(ov >> 15);
    int v2 = (int)(ov & 32767);
    int z = v2 >> 10, y = (v2 >> 5) & 31, xk = v2 & 31;

    int g = c >> 1;
    float ce   = fmaxf(stats[OFF_CNT1 + b] * 2.f, 1.f);
    float mean = stats[OFF_S1A + b * 32 + g] / ce;
    float var  = stats[OFF_S2A + b * 32 + g] / ce - mean * mean;
    float rinv = rsqrtf(var + 1e-5f);
    float a  = rinv * gn1w[c];
    float bc = gn1b[c] - mean * a;

    const int*   mb = mask + ((size_t)b << 18);
    const float* xb = x + (((size_t)b << 18) << 6);

    float hacc = 0.f, xacc = 0.f; int cnt = 0;
    #pragma unroll
    for (int dz = 0; dz < 2; ++dz)
    #pragma unroll
    for (int dy = 0; dy < 2; ++dy)
    #pragma unroll
    for (int dx = 0; dx < 2; ++dx) {
        int v1 = ((2 * z + dz) << 12) | ((2 * y + dy) << 6) | (2 * xk + dx);
        if (mb[v1]) {
            cnt++;
            float xv = xb[(size_t)v1 * 64 + c];
            xacc += xv;
            float yv = fmaf(xv, a, bc);
            hacc += yv / (1.f + expf(-yv));
        }
    }
    float inv = 1.f / fmaxf((float)cnt, 1.f);
    int pvox = (z + 1) * P2_ + (y + 1) * P_ + (xk + 1);
    size_t so = ((size_t)(c >> 5) * SBSTRIDE + (size_t)b * P3_ + pvox) * 32 + (c & 31);
    h1p[so] = f2bf(hacc * inv);
    xdb[ov * 64 + c] = f2bf(xacc * inv);
    if (c == 0) dm[ov] = (cnt > 0) ? 1.f : 0.f;
}

// ---------------- MFMA implicit-GEMM conv 3x3x3 (+optional 1x1 skip taps) ----------------
// BK=64 phases: 2 K-steps per barrier. W pair (16KB) staged via global_load_lds
// (width=16, linear) into double-buffered LDS; counted vmcnt(4) before the single
// per-phase barrier keeps next-phase A loads in flight (T3+T4). setprio on MFMA (T5).
template<int CIN, bool SKIP>
__global__ __launch_bounds__(256, 4) void conv3_mfma(
    const unsigned short* __restrict__ srcP,   // padded [CS][4][34^3][32]
    const unsigned short* __restrict__ sksrc,  // flat [TOTV][64] (skip) or null
    const unsigned short* __restrict__ wT,
    const int* __restrict__ tblA,
    const float* __restrict__ bias,
    const float* __restrict__ bias2,
    const float* __restrict__ dm,
    float* __restrict__ outf,
    unsigned short* __restrict__ outb)
{
    constexpr int CS   = CIN / 32;
    constexpr int NKM  = 27 * CS;                 // main K-steps (even)
    constexpr int NPHM = NKM / 2;                 // main phases
    constexpr int NPH  = NPHM + (SKIP ? 1 : 0);   // total phases

    __shared__ short smem[2][8192];   // 2 x 16KB W slab-pairs

    const int tid  = threadIdx.x;
    const int lane = tid & 63;
    const int wv   = tid >> 6;
    // XCD-aware bijective swizzle: 1024 blocks, 8 XCDs, 128-block chunks
    const int orig = blockIdx.x;
    const int blk  = (orig & 7) * 128 + (orig >> 3);
    const int b    = blk >> 8;
    const int z    = (blk >> 3) & 31;
    const int yo   = blk & 7;
    const int y0   = yo * 4 + wv;      // this wave's y-row
    const int vb   = b * 32768;
    const int klo  = (lane >> 4) * 8;
    const int xl   = lane & 15;
    const int rlo  = (lane >> 4) * 4;

    f32x4 acc[2][8];
    #pragma unroll
    for (int f = 0; f < 2; ++f)
        #pragma unroll
        for (int nb = 0; nb < 8; ++nb)
            acc[f][nb] = (f32x4){0.f, 0.f, 0.f, 0.f};

    // per-lane A pointer at step 0 (tap dz=dy=dx=0, s=0): padded coords (z, y0, xl)
    const char* pA = (const char*)srcP +
        (((size_t)b * P3_ + (size_t)(z * P2_ + y0 * P_ + xl)) * 32 + klo) * 2;

    // skip-phase A loader (flat xdb, center tap, always in bounds)
    auto loadSkip = [&](int ss, bf16x8* af) {
        const unsigned short* abase = sksrc + ss * 32;
        #pragma unroll
        for (int f = 0; f < 2; ++f) {
            int xx = f * 16 + xl;
            af[f] = *(const bf16x8*)(abase +
                     (size_t)(vb + z * 1024 + y0 * 32 + xx) * 64 + klo);
        }
    };

    // stage W slab-pair `pr` into LDS buffer `buf` via global_load_lds (4 x 16B/thread)
    auto stageW = [&](int pr, int buf) {
        const char* g = (const char*)wT + (size_t)pr * 16384 + wv * 1024 + (lane << 4);
        char* l = (char*)&smem[0][0] + buf * 16384 + wv * 1024;
        #pragma unroll
        for (int j = 0; j < 4; ++j)
            __builtin_amdgcn_global_load_lds(
                (const __attribute__((address_space(1))) unsigned int*)(g + j * 4096),
                (__attribute__((address_space(3))) unsigned int*)(l + j * 4096),
                16, 0, 0);
    };

    // ---- prologue: W pair 0 -> LDS[0], A steps 0,1 -> afc ----
    bf16x8 afc[4];
    stageW(0, 0);
    afc[0] = *(const bf16x8*)pA; afc[1] = *(const bf16x8*)(pA + 1024); pA += tblA[0];
    afc[2] = *(const bf16x8*)pA; afc[3] = *(const bf16x8*)(pA + 1024); pA += tblA[1];
    asm volatile("s_waitcnt vmcnt(4)" ::: "memory");
    __builtin_amdgcn_s_barrier();

    int cur = 0;
    #pragma unroll 2
    for (int p = 0; p < NPH; ++p) {
        const bool more = (p + 1 < NPH);
        // issue-early: W pair p+1 -> LDS[cur^1]; A for phase p+1 -> afn
        bf16x8 afn[4] = {{}, {}, {}, {}};
        if (more) {
            stageW(p + 1, cur ^ 1);
            if (2 * p + 2 < NKM) {
                afn[0] = *(const bf16x8*)pA; afn[1] = *(const bf16x8*)(pA + 1024);
                pA += tblA[2 * p + 2];
                afn[2] = *(const bf16x8*)pA; afn[3] = *(const bf16x8*)(pA + 1024);
                pA += tblA[2 * p + 3];
            } else if (SKIP) {
                loadSkip(0, &afn[0]);
                loadSkip(1, &afn[2]);
            }
        }
        // MFMA cluster: 2 sub-steps x 8 n-frags x 2 m-frags = 32 MFMA
        __builtin_amdgcn_s_setprio(1);
        #pragma unroll
        for (int ss = 0; ss < 2; ++ss) {
            const short* bp = &smem[0][0] + cur * 8192 + ss * 4096 +
                              ((lane >> 4) * 128 + xl) * 8;
            #pragma unroll
            for (int nb = 0; nb < 8; ++nb) {
                bf16x8 bfr = *(const bf16x8*)(bp + nb * 128);
                acc[0][nb] = __builtin_amdgcn_mfma_f32_16x16x32_bf16(afc[ss * 2 + 0], bfr, acc[0][nb], 0, 0, 0);
                acc[1][nb] = __builtin_amdgcn_mfma_f32_16x16x32_bf16(afc[ss * 2 + 1], bfr, acc[1][nb], 0, 0, 0);
            }
        }
        __builtin_amdgcn_s_setprio(0);
        // counted drain: W gloads (oldest 4) done; A loads stay in flight
        if (more) asm volatile("s_waitcnt vmcnt(4)" ::: "memory");
        else      asm volatile("s_waitcnt vmcnt(0)" ::: "memory");
        asm volatile("s_waitcnt lgkmcnt(0)" ::: "memory");
        __builtin_amdgcn_s_barrier();
        afc[0] = afn[0]; afc[1] = afn[1]; afc[2] = afn[2]; afc[3] = afn[3];
        cur ^= 1;
    }

    // ---- epilogue ----
    float bv[8];
    #pragma unroll
    for (int nb = 0; nb < 8; ++nb) {
        int co = nb * 16 + xl;
        if constexpr (SKIP) bv[nb] = bias[co] + bias2[co];
        else                bv[nb] = bias[co];
    }
    #pragma unroll
    for (int f = 0; f < 2; ++f) {
        int xb2 = f * 16 + rlo;
        #pragma unroll
        for (int j = 0; j < 4; ++j) {
            int vox = vb + z * 1024 + y0 * 32 + xb2 + j;
            float dmx = dm[vox];
            #pragma unroll
            for (int nb = 0; nb < 8; ++nb) {
                float o = (acc[f][nb][j] + bv[nb]) * dmx;
                if constexpr (SKIP) outf[(size_t)vox * 128 + nb * 16 + xl] = o;
                else                outb[(size_t)vox * 128 + nb * 16 + xl] = f2bf(o);
            }
        }
    }
}

// ---------------- Kernel 4: GN2 stats over h2a (flat bf16) ----------------
__global__ __launch_bounds__(256) void k4_stats2(const unsigned short* __restrict__ h2a,
                                                 const float* __restrict__ dm,
                                                 float* __restrict__ stats)
{
    __shared__ float ls1[32], ls2[32];
    __shared__ float lcnt;
    int tid = threadIdx.x;
    if (tid < 32) { ls1[tid] = 0.f; ls2[tid] = 0.f; }
    if (tid == 0) lcnt = 0.f;
    __syncthreads();

    int b  = blockIdx.x & 3;
    int bb = blockIdx.x >> 2;
    int g  = tid & 31;
    int vl = tid >> 5;

    const unsigned short* hb = h2a + ((size_t)b * V2) * C2;
    const float* dmb = dm + (size_t)b * V2;

    float s1 = 0.f, s2 = 0.f, mc = 0.f;
    for (int ch = bb; ch < V2 / 8; ch += 1024) {
        int v = ch * 8 + vl;
        float m = dmb[v];
        if (g == 0) mc += m;
        if (m != 0.f) {
            ushort4 hv = *(const ushort4*)(hb + (size_t)v * C2 + g * 4);
            float h0 = bf2f(hv.x), h1 = bf2f(hv.y), h2 = bf2f(hv.z), h3 = bf2f(hv.w);
            s1 += h0 + h1 + h2 + h3;
            s2 += h0 * h0 + h1 * h1 + h2 * h2 + h3 * h3;
        }
    }
    atomicAdd(&ls1[g], s1); atomicAdd(&ls2[g], s2);
    if (g == 0) atomicAdd(&lcnt, mc);
    __syncthreads();
    if (tid < 32) {
        atomicAdd(&stats[OFF_S1B + b * 32 + tid], ls1[tid]);
        atomicAdd(&stats[OFF_S2B + b * 32 + tid], ls2[tid]);
    }
    if (tid == 0) atomicAdd(&stats[OFF_CNT2 + b], lcnt);
}

// ---------------- Kernel 5: GN2 apply + SiLU -> h2p (padded sliced bf16) ----------------
__global__ __launch_bounds__(256) void k5_gn2(const unsigned short* __restrict__ h2a,
                                              unsigned short* __restrict__ h2p,
                                              const float* __restrict__ stats,
                                              const float* __restrict__ dm,
                                              const float* __restrict__ gn2w,
                                              const float* __restrict__ gn2b)
{
    int idx = blockIdx.x * 256 + threadIdx.x;   // group-quad index
    int v = idx >> 5, g = idx & 31;
    int b = v >> 15;
    int v2 = v & 32767;
    float ce   = fmaxf(stats[OFF_CNT2 + b] * 4.f, 1.f);
    float mean = stats[OFF_S1B + b * 32 + g] / ce;
    float var  = stats[OFF_S2B + b * 32 + g] / ce - mean * mean;
    float rinv = rsqrtf(var + 1e-5f);
    float dmv  = dm[v];
    ushort4 hv = *(const ushort4*)(h2a + (size_t)idx * 4);
    float4 gw = *(const float4*)(gn2w + g * 4);
    float4 gb = *(const float4*)(gn2b + g * 4);
    float a, t;
    ushort4 o;
    a = rinv * gw.x; t = (fmaf(bf2f(hv.x), a, gb.x - mean * a)) * dmv; o.x = f2bf(t / (1.f + expf(-t)));
    a = rinv * gw.y; t = (fmaf(bf2f(hv.y), a, gb.y - mean * a)) * dmv; o.y = f2bf(t / (1.f + expf(-t)));
    a = rinv * gw.z; t = (fmaf(bf2f(hv.z), a, gb.z - mean * a)) * dmv; o.z = f2bf(t / (1.f + expf(-t)));
    a = rinv * gw.w; t = (fmaf(bf2f(hv.w), a, gb.w - mean * a)) * dmv; o.w = f2bf(t / (1.f + expf(-t)));
    int zz = v2 >> 10, yy = (v2 >> 5) & 31, xx = v2 & 31;
    int pvox = (zz + 1) * P2_ + (yy + 1) * P_ + (xx + 1);
    size_t so = ((size_t)(g >> 3) * SBSTRIDE + (size_t)b * P3_ + pvox) * 32 + (g & 7) * 4;
    *(ushort4*)(h2p + so) = o;
}

extern "C" void kernel_launch(void* const* d_in, const int* in_sizes, int n_in,
                              void* d_out, int out_size, void* d_ws, size_t ws_size,
                              hipStream_t stream)
{
    const float* x     = (const float*)d_in[0];
    const int*   mask  = (const int*)d_in[1];
    const float* gn1w  = (const float*)d_in[2];
    const float* gn1b  = (const float*)d_in[3];
    const float* w1    = (const float*)d_in[4];
    const float* b1    = (const float*)d_in[5];
    const float* gn2w  = (const float*)d_in[6];
    const float* gn2b  = (const float*)d_in[7];
    const float* w2    = (const float*)d_in[8];
    const float* b2    = (const float*)d_in[9];
    const float* wskip = (const float*)d_in[10];
    const float* bskip = (const float*)d_in[11];
    float* out = (float*)d_out;

    char* wsb = (char*)d_ws;
    float*          stats = (float*)wsb;                           // 520 f32
    float*          dm    = (float*)(wsb + 4096);                  // 131072 f32
    unsigned short* h1p   = (unsigned short*)(wsb + 528384);       // 8 sb x 34^3 x 32
    unsigned short* xdb   = (unsigned short*)(wsb + 20652032);     // [TOTV][64]
    unsigned short* h2a   = (unsigned short*)(wsb + 37429248);     // [TOTV][128]
    unsigned short* h2p   = (unsigned short*)(wsb + 70983680);     // 16 sb x 34^3 x 32
    unsigned short* w1t   = (unsigned short*)(wsb + 111230976);    // 54*4096
    unsigned short* w2t   = (unsigned short*)(wsb + 111673344);    // 110*4096
    int*            d1    = (int*)(wsb + 112574464);               // 54 ints
    int*            d2    = (int*)(wsb + 112574720);               // 108 ints

    hipMemsetAsync(stats, 0, 520 * sizeof(float), stream);

    hipLaunchKernelGGL(k0_wprep, dim3(2624), dim3(256), 0, stream, w1, w2, wskip, w1t, w2t, d1, d2);
    hipLaunchKernelGGL(kz_border, dim3((24 * P3_ + 255) / 256), dim3(256), 0, stream, h1p, h2p);
    hipLaunchKernelGGL(k1_stats1, dim3(4096), dim3(256), 0, stream, x, mask, stats);
    hipLaunchKernelGGL(k2_down, dim3(32768), dim3(256), 0, stream,
                       x, mask, gn1w, gn1b, stats, h1p, xdb, dm);
    hipLaunchKernelGGL((conv3_mfma<64, false>), dim3(1024), dim3(256), 0, stream,
                       h1p, (const unsigned short*)nullptr, w1t, d1, b1, (const float*)nullptr,
                       dm, (float*)nullptr, h2a);
    hipLaunchKernelGGL(k4_stats2, dim3(4096), dim3(256), 0, stream, h2a, dm, stats);
    hipLaunchKernelGGL(k5_gn2, dim3(16384), dim3(256), 0, stream, h2a, h2p, stats, dm, gn2w, gn2b);
    hipLaunchKernelGGL((conv3_mfma<128, true>), dim3(1024), dim3(256), 0, stream,
                       h2p, xdb, w2t, d2, b2, bskip, dm, out, (unsigned short*)nullptr);
}

// Round 12
// 441.235 us; speedup vs baseline: 1.6823x; 1.0020x over previous
//
#include <hip/hip_runtime.h>
#include <cstdint>
#include <cstddef>

#define B_ 4
#define V1 262144   // 64^3
#define C1 64
#define V2 32768    // 32^3
#define C2 128
#define TOTV 131072
#define P_ 34
#define P2_ 1156
#define P3_ 39304
#define SBSTRIDE ((size_t)4 * P3_)   // slice stride in voxel-records ([s][b] layout)

// stats layout (float indices within stats buffer)
#define OFF_S1A 0
#define OFF_S2A 128
#define OFF_CNT1 256
#define OFF_S1B 260
#define OFF_S2B 388
#define OFF_CNT2 516

typedef __bf16 bf16x8 __attribute__((ext_vector_type(8)));
typedef float f32x4 __attribute__((ext_vector_type(4)));

__device__ __forceinline__ float bf2f(unsigned short u) {
    return __builtin_bit_cast(float, (unsigned)u << 16);
}
__device__ __forceinline__ unsigned short f2bf(float f) {
    unsigned u = __builtin_bit_cast(unsigned, f);
    u += 0x7fffu + ((u >> 16) & 1u);     // RTNE
    return (unsigned short)(u >> 16);
}

// byte offset of main-step ks's A-base (lane-independent part), CS = 1<<csh
__device__ __forceinline__ int a_ofs(int ks, int csh) {
    int s = ks & ((1 << csh) - 1), tap = ks >> csh;
    int dz = tap / 9, r = tap % 9, dy = r / 3, dx = r % 3;
    return s * (int)(SBSTRIDE * 64) + (dz * P2_ + dy * P_ + dx) * 64;
}

// ---------------- Kernel 0: weight prep + A-delta tables ----------------
// Slabs tap-major: slab = t*CS + s. Within slab: [q4][n128][j8], k=q*8+j, n=co.
__global__ __launch_bounds__(256) void k0_wprep(const float* __restrict__ w1,
                                                const float* __restrict__ w2,
                                                const float* __restrict__ wskip,
                                                unsigned short* __restrict__ w1t,
                                                unsigned short* __restrict__ w2t,
                                                int* __restrict__ d1,
                                                int* __restrict__ d2)
{
    int i = blockIdx.x * 256 + threadIdx.x;
    if (blockIdx.x == 0) {
        int t = threadIdx.x;
        if (t < 54)               d1[t] = (t + 1 < 54)  ? a_ofs(t + 1, 1) - a_ofs(t, 1) : 0;
        if (t >= 64 && t < 172) { int j = t - 64;
                                  d2[j] = (j + 1 < 108) ? a_ofs(j + 1, 2) - a_ofs(j, 2) : 0; }
    }
    if (i < 54 * 4096) {
        int slab = i >> 12, r = i & 4095;
        int q = r >> 10, n = (r >> 3) & 127, j = r & 7;
        int t = slab >> 1, s = slab & 1;
        int ci = s * 32 + q * 8 + j;
        w1t[i] = f2bf(w1[((size_t)t * 64 + ci) * 128 + n]);
    }
    int i2 = i - 54 * 4096;
    if (i2 >= 0 && i2 < 110 * 4096) {
        int slab = i2 >> 12, r = i2 & 4095;
        int q = r >> 10, n = (r >> 3) & 127, j = r & 7;
        float v;
        if (slab < 108) {
            int t = slab >> 2, s = slab & 3;
            int ci = s * 32 + q * 8 + j;
            v = w2[((size_t)t * 128 + ci) * 128 + n];
        } else {
            int ci = (slab - 108) * 32 + q * 8 + j;
            v = wskip[(size_t)ci * 128 + n];
        }
        w2t[i2] = f2bf(v);
    }
}

// ---------------- Kernel Z: zero padded-buffer borders (h1p: 8 sb, h2p: 16 sb) ----------------
__global__ __launch_bounds__(256) void kz_border(unsigned short* __restrict__ h1p,
                                                 unsigned short* __restrict__ h2p)
{
    int i = blockIdx.x * 256 + threadIdx.x;      // one voxel-record per thread
    if (i >= 24 * P3_) return;
    int sb = i / P3_, vox = i % P3_;
    int vz = vox / P2_, r = vox % P2_, vy = r / P_, vx = r % P_;
    bool border = (vz == 0) | (vz == 33) | (vy == 0) | (vy == 33) | (vx == 0) | (vx == 33);
    if (!border) return;
    unsigned short* base = (sb < 8) ? (h1p + (size_t)sb * P3_ * 32 + (size_t)vox * 32)
                                    : (h2p + (size_t)(sb - 8) * P3_ * 32 + (size_t)vox * 32);
    uint4 z = {0, 0, 0, 0};
    uint4* b4 = (uint4*)base;
    b4[0] = z; b4[1] = z; b4[2] = z; b4[3] = z;
}

// ---------------- Kernel 1: GN1 stats ----------------
__global__ __launch_bounds__(256) void k1_stats1(const float* __restrict__ x,
                                                 const int* __restrict__ mask,
                                                 float* __restrict__ stats)
{
    __shared__ float ls1[32], ls2[32];
    __shared__ float lcnt;
    int tid = threadIdx.x;
    if (tid < 32) { ls1[tid] = 0.f; ls2[tid] = 0.f; }
    if (tid == 0) lcnt = 0.f;
    __syncthreads();

    int b  = blockIdx.x & 3;
    int bb = blockIdx.x >> 2;
    int c4 = tid & 15;
    int vl = tid >> 4;

    const float* xb = x + ((size_t)b * V1) * C1;
    const int*   mb = mask + (size_t)b * V1;

    float s1a = 0.f, s2a = 0.f, s1b = 0.f, s2b = 0.f, mc = 0.f;
    for (int ch = bb; ch < V1 / 16; ch += 1024) {
        int v = ch * 16 + vl;
        int m = mb[v];
        if (c4 == 0) mc += (float)m;
        if (m) {
            float4 xv = *(const float4*)(xb + (size_t)v * C1 + c4 * 4);
            s1a += xv.x + xv.y;  s2a += xv.x * xv.x + xv.y * xv.y;
            s1b += xv.z + xv.w;  s2b += xv.z * xv.z + xv.w * xv.w;
        }
    }
    atomicAdd(&ls1[2 * c4],     s1a); atomicAdd(&ls2[2 * c4],     s2a);
    atomicAdd(&ls1[2 * c4 + 1], s1b); atomicAdd(&ls2[2 * c4 + 1], s2b);
    if (c4 == 0) atomicAdd(&lcnt, mc);
    __syncthreads();
    if (tid < 32) {
        atomicAdd(&stats[OFF_S1A + b * 32 + tid], ls1[tid]);
        atomicAdd(&stats[OFF_S2A + b * 32 + tid], ls2[tid]);
    }
    if (tid == 0) atomicAdd(&stats[OFF_CNT1 + b], lcnt);
}

// ------ Kernel 2: GN1 apply + SiLU + downsample -> h1p (padded sliced), xdb (flat), dm ------
__global__ __launch_bounds__(256) void k2_down(const float* __restrict__ x,
                                               const int* __restrict__ mask,
                                               const float* __restrict__ gn1w,
                                               const float* __restrict__ gn1b,
                                               const float* __restrict__ stats,
                                               unsigned short* __restrict__ h1p,
                                               unsigned short* __restrict__ xdb,
                                               float* __restrict__ dm)
{
    int tid = threadIdx.x;
    int c  = tid & 63;
    int vl = tid >> 6;
    size_t ov = (size_t)blockIdx.x * 4 + vl;
    int b  = (int)(ov >> 15);
    int v2 = (int)(ov & 32767);
    int z = v2 >> 10, y = (v2 >> 5) & 31, xk = v2 & 31;

    int g = c >> 1;
    float ce   = fmaxf(stats[OFF_CNT1 + b] * 2.f, 1.f);
    float mean = stats[OFF_S1A + b * 32 + g] / ce;
    float var  = stats[OFF_S2A + b * 32 + g] / ce - mean * mean;
    float rinv = rsqrtf(var + 1e-5f);
    float a  = rinv * gn1w[c];
    float bc = gn1b[c] - mean * a;

    const int*   mb = mask + ((size_t)b << 18);
    const float* xb = x + (((size_t)b << 18) << 6);

    float hacc = 0.f, xacc = 0.f; int cnt = 0;
    #pragma unroll
    for (int dz = 0; dz < 2; ++dz)
    #pragma unroll
    for (int dy = 0; dy < 2; ++dy)
    #pragma unroll
    for (int dx = 0; dx < 2; ++dx) {
        int v1 = ((2 * z + dz) << 12) | ((2 * y + dy) << 6) | (2 * xk + dx);
        if (mb[v1]) {
            cnt++;
            float xv = xb[(size_t)v1 * 64 + c];
            xacc += xv;
            float yv = fmaf(xv, a, bc);
            hacc += yv / (1.f + expf(-yv));
        }
    }
    float inv = 1.f / fmaxf((float)cnt, 1.f);
    int pvox = (z + 1) * P2_ + (y + 1) * P_ + (xk + 1);
    size_t so = ((size_t)(c >> 5) * SBSTRIDE + (size_t)b * P3_ + pvox) * 32 + (c & 31);
    h1p[so] = f2bf(hacc * inv);
    xdb[ov * 64 + c] = f2bf(xacc * inv);
    if (c == 0) dm[ov] = (cnt > 0) ? 1.f : 0.f;
}

// ---------------- MFMA implicit-GEMM conv 3x3x3 (+optional 1x1 skip taps) ----------------
// Wave tile M=64 (2 y-rows) x N=128: acc[4][8] = 128 VGPR; 32 MFMA per K-step vs
// 8 ds_read_b128 -> LDS-read/MFMA ratio 0.25 (matrix-bound). Block = 4 waves =
// M=256 (8 y-rows at one (b,z)). BK=64 phases, W via global_load_lds (dbuf),
// counted vmcnt(8) keeps 8 A-loads in flight across the barrier; setprio on MFMA.
template<int CIN, bool SKIP>
__global__ __launch_bounds__(256, 2) void conv3_mfma(
    const unsigned short* __restrict__ srcP,   // padded [CS][4][34^3][32]
    const unsigned short* __restrict__ sksrc,  // flat [TOTV][64] (skip) or null
    const unsigned short* __restrict__ wT,
    const int* __restrict__ tblA,
    const float* __restrict__ bias,
    const float* __restrict__ bias2,
    const float* __restrict__ dm,
    float* __restrict__ outf,
    unsigned short* __restrict__ outb)
{
    constexpr int CS   = CIN / 32;
    constexpr int NKM  = 27 * CS;                 // main K-steps (even)
    constexpr int NPHM = NKM / 2;                 // main phases
    constexpr int NPH  = NPHM + (SKIP ? 1 : 0);   // total phases

    __shared__ short smem[2][8192];   // 2 x 16KB W slab-pairs

    const int tid  = threadIdx.x;
    const int lane = tid & 63;
    const int wv   = tid >> 6;
    // XCD-aware bijective swizzle: 512 blocks, 8 XCDs, 64-block chunks
    const int orig = blockIdx.x;
    const int blk  = (orig & 7) * 64 + (orig >> 3);
    const int b    = blk >> 7;
    const int z    = (blk >> 2) & 31;
    const int yo   = blk & 3;
    const int y0   = yo * 8 + wv * 2;  // this wave's first y-row (owns rows y0, y0+1)
    const int vb   = b * 32768;
    const int klo  = (lane >> 4) * 8;
    const int xl   = lane & 15;
    const int rlo  = (lane >> 4) * 4;

    f32x4 acc[4][8];
    #pragma unroll
    for (int f = 0; f < 4; ++f)
        #pragma unroll
        for (int nb = 0; nb < 8; ++nb)
            acc[f][nb] = (f32x4){0.f, 0.f, 0.f, 0.f};

    // per-lane A pointer at step 0 (tap dz=dy=dx=0, s=0): padded coords (z, y0, xl)
    // (first tap reads source coord -1 in each dim; padded index = coord+1)
    const char* pA = (const char*)srcP +
        (((size_t)b * P3_ + (size_t)(z * P2_ + y0 * P_ + xl)) * 32 + klo) * 2;
    // frag offsets within a step: fx half = +1024B, next y-row = +P_*64 = 2176B

    // skip-phase A loader (flat xdb, center tap, always in bounds): 4 frags
    auto loadSkip = [&](int ss, bf16x8* af) {
        const unsigned short* abase = sksrc + ss * 32;
        #pragma unroll
        for (int fy = 0; fy < 2; ++fy)
            #pragma unroll
            for (int fx = 0; fx < 2; ++fx)
                af[fy * 2 + fx] = *(const bf16x8*)(abase +
                    (size_t)(vb + z * 1024 + (y0 + fy) * 32 + fx * 16 + xl) * 64 + klo);
    };

    // stage W slab-pair `pr` into LDS buffer `buf` via global_load_lds (4 x 16B/thread)
    auto stageW = [&](int pr, int buf) {
        const char* g = (const char*)wT + (size_t)pr * 16384 + wv * 1024 + (lane << 4);
        char* l = (char*)&smem[0][0] + buf * 16384 + wv * 1024;
        #pragma unroll
        for (int j = 0; j < 4; ++j)
            __builtin_amdgcn_global_load_lds(
                (const __attribute__((address_space(1))) unsigned int*)(g + j * 4096),
                (__attribute__((address_space(3))) unsigned int*)(l + j * 4096),
                16, 0, 0);
    };

    // load A frags (4) for one main K-step at current pA, then advance
    auto loadAStep = [&](int ks, bf16x8* af) {
        af[0] = *(const bf16x8*)pA;
        af[1] = *(const bf16x8*)(pA + 1024);
        af[2] = *(const bf16x8*)(pA + 2176);
        af[3] = *(const bf16x8*)(pA + 3200);
        pA += tblA[ks];
    };

    // ---- prologue: W pair 0 -> LDS[0], A steps 0,1 -> afc ----
    bf16x8 afc[8];
    stageW(0, 0);
    loadAStep(0, &afc[0]);
    loadAStep(1, &afc[4]);
    asm volatile("s_waitcnt vmcnt(8)" ::: "memory");
    __builtin_amdgcn_s_barrier();

    int cur = 0;
    #pragma unroll 2
    for (int p = 0; p < NPH; ++p) {
        const bool more = (p + 1 < NPH);
        // issue-early: W pair p+1 -> LDS[cur^1]; A for phase p+1 -> afn
        bf16x8 afn[8] = {{}, {}, {}, {}, {}, {}, {}, {}};
        if (more) {
            stageW(p + 1, cur ^ 1);
            if (2 * p + 2 < NKM) {
                loadAStep(2 * p + 2, &afn[0]);
                loadAStep(2 * p + 3, &afn[4]);
            } else if (SKIP) {
                loadSkip(0, &afn[0]);
                loadSkip(1, &afn[4]);
            }
        }
        // MFMA cluster: 2 sub-steps x 8 n-frags x 4 m-frags = 64 MFMA
        __builtin_amdgcn_s_setprio(1);
        #pragma unroll
        for (int ss = 0; ss < 2; ++ss) {
            const short* bp = &smem[0][0] + cur * 8192 + ss * 4096 +
                              ((lane >> 4) * 128 + xl) * 8;
            #pragma unroll
            for (int nb = 0; nb < 8; ++nb) {
                bf16x8 bfr = *(const bf16x8*)(bp + nb * 128);
                acc[0][nb] = __builtin_amdgcn_mfma_f32_16x16x32_bf16(afc[ss * 4 + 0], bfr, acc[0][nb], 0, 0, 0);
                acc[1][nb] = __builtin_amdgcn_mfma_f32_16x16x32_bf16(afc[ss * 4 + 1], bfr, acc[1][nb], 0, 0, 0);
                acc[2][nb] = __builtin_amdgcn_mfma_f32_16x16x32_bf16(afc[ss * 4 + 2], bfr, acc[2][nb], 0, 0, 0);
                acc[3][nb] = __builtin_amdgcn_mfma_f32_16x16x32_bf16(afc[ss * 4 + 3], bfr, acc[3][nb], 0, 0, 0);
            }
        }
        __builtin_amdgcn_s_setprio(0);
        // counted drain: W gloads (oldest 4) done; 8 A loads stay in flight
        if (more) asm volatile("s_waitcnt vmcnt(8)" ::: "memory");
        else      asm volatile("s_waitcnt vmcnt(0)" ::: "memory");
        asm volatile("s_waitcnt lgkmcnt(0)" ::: "memory");
        __builtin_amdgcn_s_barrier();
        #pragma unroll
        for (int j = 0; j < 8; ++j) afc[j] = afn[j];
        cur ^= 1;
    }

    // ---- epilogue ----
    float bv[8];
    #pragma unroll
    for (int nb = 0; nb < 8; ++nb) {
        int co = nb * 16 + xl;
        if constexpr (SKIP) bv[nb] = bias[co] + bias2[co];
        else                bv[nb] = bias[co];
    }
    #pragma unroll
    for (int f = 0; f < 4; ++f) {
        const int fy = f >> 1, fx = f & 1;
        const int vox0 = vb + z * 1024 + (y0 + fy) * 32 + fx * 16 + rlo;
        float4 dm4 = *(const float4*)(dm + vox0);
        #pragma unroll
        for (int j = 0; j < 4; ++j) {
            const float dmx = (j == 0) ? dm4.x : (j == 1) ? dm4.y : (j == 2) ? dm4.z : dm4.w;
            const size_t obase = (size_t)(vox0 + j) * 128 + xl;
            #pragma unroll
            for (int nb = 0; nb < 8; ++nb) {
                float o = (acc[f][nb][j] + bv[nb]) * dmx;
                if constexpr (SKIP) outf[obase + nb * 16] = o;
                else                outb[obase + nb * 16] = f2bf(o);
            }
        }
    }
}

// ---------------- Kernel 4: GN2 stats over h2a (flat bf16) ----------------
__global__ __launch_bounds__(256) void k4_stats2(const unsigned short* __restrict__ h2a,
                                                 const float* __restrict__ dm,
                                                 float* __restrict__ stats)
{
    __shared__ float ls1[32], ls2[32];
    __shared__ float lcnt;
    int tid = threadIdx.x;
    if (tid < 32) { ls1[tid] = 0.f; ls2[tid] = 0.f; }
    if (tid == 0) lcnt = 0.f;
    __syncthreads();

    int b  = blockIdx.x & 3;
    int bb = blockIdx.x >> 2;
    int g  = tid & 31;
    int vl = tid >> 5;

    const unsigned short* hb = h2a + ((size_t)b * V2) * C2;
    const float* dmb = dm + (size_t)b * V2;

    float s1 = 0.f, s2 = 0.f, mc = 0.f;
    for (int ch = bb; ch < V2 / 8; ch += 1024) {
        int v = ch * 8 + vl;
        float m = dmb[v];
        if (g == 0) mc += m;
        if (m != 0.f) {
            ushort4 hv = *(const ushort4*)(hb + (size_t)v * C2 + g * 4);
            float h0 = bf2f(hv.x), h1 = bf2f(hv.y), h2 = bf2f(hv.z), h3 = bf2f(hv.w);
            s1 += h0 + h1 + h2 + h3;
            s2 += h0 * h0 + h1 * h1 + h2 * h2 + h3 * h3;
        }
    }
    atomicAdd(&ls1[g], s1); atomicAdd(&ls2[g], s2);
    if (g == 0) atomicAdd(&lcnt, mc);
    __syncthreads();
    if (tid < 32) {
        atomicAdd(&stats[OFF_S1B + b * 32 + tid], ls1[tid]);
        atomicAdd(&stats[OFF_S2B + b * 32 + tid], ls2[tid]);
    }
    if (tid == 0) atomicAdd(&stats[OFF_CNT2 + b], lcnt);
}

// ---------------- Kernel 5: GN2 apply + SiLU -> h2p (padded sliced bf16) ----------------
__global__ __launch_bounds__(256) void k5_gn2(const unsigned short* __restrict__ h2a,
                                              unsigned short* __restrict__ h2p,
                                              const float* __restrict__ stats,
                                              const float* __restrict__ dm,
                                              const float* __restrict__ gn2w,
                                              const float* __restrict__ gn2b)
{
    int idx = blockIdx.x * 256 + threadIdx.x;   // group-quad index
    int v = idx >> 5, g = idx & 31;
    int b = v >> 15;
    int v2 = v & 32767;
    float ce   = fmaxf(stats[OFF_CNT2 + b] * 4.f, 1.f);
    float mean = stats[OFF_S1B + b * 32 + g] / ce;
    float var  = stats[OFF_S2B + b * 32 + g] / ce - mean * mean;
    float rinv = rsqrtf(var + 1e-5f);
    float dmv  = dm[v];
    ushort4 hv = *(const ushort4*)(h2a + (size_t)idx * 4);
    float4 gw = *(const float4*)(gn2w + g * 4);
    float4 gb = *(const float4*)(gn2b + g * 4);
    float a, t;
    ushort4 o;
    a = rinv * gw.x; t = (fmaf(bf2f(hv.x), a, gb.x - mean * a)) * dmv; o.x = f2bf(t / (1.f + expf(-t)));
    a = rinv * gw.y; t = (fmaf(bf2f(hv.y), a, gb.y - mean * a)) * dmv; o.y = f2bf(t / (1.f + expf(-t)));
    a = rinv * gw.z; t = (fmaf(bf2f(hv.z), a, gb.z - mean * a)) * dmv; o.z = f2bf(t / (1.f + expf(-t)));
    a = rinv * gw.w; t = (fmaf(bf2f(hv.w), a, gb.w - mean * a)) * dmv; o.w = f2bf(t / (1.f + expf(-t)));
    int zz = v2 >> 10, yy = (v2 >> 5) & 31, xx = v2 & 31;
    int pvox = (zz + 1) * P2_ + (yy + 1) * P_ + (xx + 1);
    size_t so = ((size_t)(g >> 3) * SBSTRIDE + (size_t)b * P3_ + pvox) * 32 + (g & 7) * 4;
    *(ushort4*)(h2p + so) = o;
}

extern "C" void kernel_launch(void* const* d_in, const int* in_sizes, int n_in,
                              void* d_out, int out_size, void* d_ws, size_t ws_size,
                              hipStream_t stream)
{
    const float* x     = (const float*)d_in[0];
    const int*   mask  = (const int*)d_in[1];
    const float* gn1w  = (const float*)d_in[2];
    const float* gn1b  = (const float*)d_in[3];
    const float* w1    = (const float*)d_in[4];
    const float* b1    = (const float*)d_in[5];
    const float* gn2w  = (const float*)d_in[6];
    const float* gn2b  = (const float*)d_in[7];
    const float* w2    = (const float*)d_in[8];
    const float* b2    = (const float*)d_in[9];
    const float* wskip = (const float*)d_in[10];
    const float* bskip = (const float*)d_in[11];
    float* out = (float*)d_out;

    char* wsb = (char*)d_ws;
    float*          stats = (float*)wsb;                           // 520 f32
    float*          dm    = (float*)(wsb + 4096);                  // 131072 f32
    unsigned short* h1p   = (unsigned short*)(wsb + 528384);       // 8 sb x 34^3 x 32
    unsigned short* xdb   = (unsigned short*)(wsb + 20652032);     // [TOTV][64]
    unsigned short* h2a   = (unsigned short*)(wsb + 37429248);     // [TOTV][128]
    unsigned short* h2p   = (unsigned short*)(wsb + 70983680);     // 16 sb x 34^3 x 32
    unsigned short* w1t   = (unsigned short*)(wsb + 111230976);    // 54*4096
    unsigned short* w2t   = (unsigned short*)(wsb + 111673344);    // 110*4096
    int*            d1    = (int*)(wsb + 112574464);               // 54 ints
    int*            d2    = (int*)(wsb + 112574720);               // 108 ints

    hipMemsetAsync(stats, 0, 520 * sizeof(float), stream);

    hipLaunchKernelGGL(k0_wprep, dim3(2624), dim3(256), 0, stream, w1, w2, wskip, w1t, w2t, d1, d2);
    hipLaunchKernelGGL(kz_border, dim3((24 * P3_ + 255) / 256), dim3(256), 0, stream, h1p, h2p);
    hipLaunchKernelGGL(k1_stats1, dim3(4096), dim3(256), 0, stream, x, mask, stats);
    hipLaunchKernelGGL(k2_down, dim3(32768), dim3(256), 0, stream,
                       x, mask, gn1w, gn1b, stats, h1p, xdb, dm);
    hipLaunchKernelGGL((conv3_mfma<64, false>), dim3(512), dim3(256), 0, stream,
                       h1p, (const unsigned short*)nullptr, w1t, d1, b1, (const float*)nullptr,
                       dm, (float*)nullptr, h2a);
    hipLaunchKernelGGL(k4_stats2, dim3(4096), dim3(256), 0, stream, h2a, dm, stats);
    hipLaunchKernelGGL(k5_gn2, dim3(16384), dim3(256), 0, stream, h2a, h2p, stats, dm, gn2w, gn2b);
    hipLaunchKernelGGL((conv3_mfma<128, true>), dim3(512), dim3(256), 0, stream,
                       h2p, xdb, w2t, d2, b2, bskip, dm, out, (unsigned short*)nullptr);
}

// Round 13
// 418.316 us; speedup vs baseline: 1.7744x; 1.0548x over previous
//
#include <hip/hip_runtime.h>
#include <cstdint>
#include <cstddef>

#define B_ 4
#define V1 262144   // 64^3
#define C1 64
#define V2 32768    // 32^3
#define C2 128
#define TOTV 131072
#define P_ 34
#define P2_ 1156
#define P3_ 39304
#define SBSTRIDE ((size_t)4 * P3_)   // slice stride in voxel-records ([s][b] layout)

// stats layout (float indices within stats buffer)
#define OFF_S1A 0
#define OFF_S2A 128
#define OFF_CNT1 256
#define OFF_S1B 260
#define OFF_S2B 388
#define OFF_CNT2 516

typedef __bf16 bf16x8 __attribute__((ext_vector_type(8)));
typedef float f32x4 __attribute__((ext_vector_type(4)));

__device__ __forceinline__ float bf2f(unsigned short u) {
    return __builtin_bit_cast(float, (unsigned)u << 16);
}
__device__ __forceinline__ unsigned short f2bf(float f) {
    unsigned u = __builtin_bit_cast(unsigned, f);
    u += 0x7fffu + ((u >> 16) & 1u);     // RTNE
    return (unsigned short)(u >> 16);
}
// fast SiLU: x * 1/(1+e^-x) using v_exp_f32 + v_rcp_f32 (err ~1e-6 rel)
__device__ __forceinline__ float fast_silu(float x) {
    return x * __builtin_amdgcn_rcpf(1.f + __expf(-x));
}

// byte offset of main-step ks's A-base (lane-independent part), CS = 1<<csh
__device__ __forceinline__ int a_ofs(int ks, int csh) {
    int s = ks & ((1 << csh) - 1), tap = ks >> csh;
    int dz = tap / 9, r = tap % 9, dy = r / 3, dx = r % 3;
    return s * (int)(SBSTRIDE * 64) + (dz * P2_ + dy * P_ + dx) * 64;
}

// ---------------- Kernel 0z: weight prep + A-delta tables + border zeroing ----------------
// blocks [0,2624): wprep; blocks [2624, 2624+3685): border zero.
__global__ __launch_bounds__(256) void k0z_prep(const float* __restrict__ w1,
                                                const float* __restrict__ w2,
                                                const float* __restrict__ wskip,
                                                unsigned short* __restrict__ w1t,
                                                unsigned short* __restrict__ w2t,
                                                int* __restrict__ d1,
                                                int* __restrict__ d2,
                                                unsigned short* __restrict__ h1p,
                                                unsigned short* __restrict__ h2p)
{
    if (blockIdx.x >= 2624) {
        int i = (blockIdx.x - 2624) * 256 + threadIdx.x;
        if (i >= 24 * P3_) return;
        int sb = i / P3_, vox = i % P3_;
        int vz = vox / P2_, r = vox % P2_, vy = r / P_, vx = r % P_;
        bool border = (vz == 0) | (vz == 33) | (vy == 0) | (vy == 33) | (vx == 0) | (vx == 33);
        if (!border) return;
        unsigned short* base = (sb < 8) ? (h1p + (size_t)sb * P3_ * 32 + (size_t)vox * 32)
                                        : (h2p + (size_t)(sb - 8) * P3_ * 32 + (size_t)vox * 32);
        uint4 z = {0, 0, 0, 0};
        uint4* b4 = (uint4*)base;
        b4[0] = z; b4[1] = z; b4[2] = z; b4[3] = z;
        return;
    }
    int i = blockIdx.x * 256 + threadIdx.x;
    if (blockIdx.x == 0) {
        int t = threadIdx.x;
        if (t < 54)               d1[t] = (t + 1 < 54)  ? a_ofs(t + 1, 1) - a_ofs(t, 1) : 0;
        if (t >= 64 && t < 172) { int j = t - 64;
                                  d2[j] = (j + 1 < 108) ? a_ofs(j + 1, 2) - a_ofs(j, 2) : 0; }
    }
    if (i < 54 * 4096) {
        int slab = i >> 12, r = i & 4095;
        int q = r >> 10, n = (r >> 3) & 127, j = r & 7;
        int t = slab >> 1, s = slab & 1;
        int ci = s * 32 + q * 8 + j;
        w1t[i] = f2bf(w1[((size_t)t * 64 + ci) * 128 + n]);
    }
    int i2 = i - 54 * 4096;
    if (i2 >= 0 && i2 < 110 * 4096) {
        int slab = i2 >> 12, r = i2 & 4095;
        int q = r >> 10, n = (r >> 3) & 127, j = r & 7;
        float v;
        if (slab < 108) {
            int t = slab >> 2, s = slab & 3;
            int ci = s * 32 + q * 8 + j;
            v = w2[((size_t)t * 128 + ci) * 128 + n];
        } else {
            int ci = (slab - 108) * 32 + q * 8 + j;
            v = wskip[(size_t)ci * 128 + n];
        }
        w2t[i2] = f2bf(v);
    }
}

// ---------------- Kernel 1: GN1 stats ----------------
__global__ __launch_bounds__(256) void k1_stats1(const float* __restrict__ x,
                                                 const int* __restrict__ mask,
                                                 float* __restrict__ stats)
{
    __shared__ float ls1[32], ls2[32];
    __shared__ float lcnt;
    int tid = threadIdx.x;
    if (tid < 32) { ls1[tid] = 0.f; ls2[tid] = 0.f; }
    if (tid == 0) lcnt = 0.f;
    __syncthreads();

    int b  = blockIdx.x & 3;
    int bb = blockIdx.x >> 2;
    int c4 = tid & 15;
    int vl = tid >> 4;

    const float* xb = x + ((size_t)b * V1) * C1;
    const int*   mb = mask + (size_t)b * V1;

    float s1a = 0.f, s2a = 0.f, s1b = 0.f, s2b = 0.f, mc = 0.f;
    for (int ch = bb; ch < V1 / 16; ch += 1024) {
        int v = ch * 16 + vl;
        int m = mb[v];
        if (c4 == 0) mc += (float)m;
        if (m) {
            float4 xv = *(const float4*)(xb + (size_t)v * C1 + c4 * 4);
            s1a += xv.x + xv.y;  s2a += xv.x * xv.x + xv.y * xv.y;
            s1b += xv.z + xv.w;  s2b += xv.z * xv.z + xv.w * xv.w;
        }
    }
    atomicAdd(&ls1[2 * c4],     s1a); atomicAdd(&ls2[2 * c4],     s2a);
    atomicAdd(&ls1[2 * c4 + 1], s1b); atomicAdd(&ls2[2 * c4 + 1], s2b);
    if (c4 == 0) atomicAdd(&lcnt, mc);
    __syncthreads();
    if (tid < 32) {
        atomicAdd(&stats[OFF_S1A + b * 32 + tid], ls1[tid]);
        atomicAdd(&stats[OFF_S2A + b * 32 + tid], ls2[tid]);
    }
    if (tid == 0) atomicAdd(&stats[OFF_CNT1 + b], lcnt);
}

// ------ Kernel 2: GN1 apply + SiLU + downsample -> h1p (padded sliced), xdb (flat), dm ------
// grid 4096; each block handles 32 consecutive output voxels (8 iterations x 4).
__global__ __launch_bounds__(256) void k2_down(const float* __restrict__ x,
                                               const int* __restrict__ mask,
                                               const float* __restrict__ gn1w,
                                               const float* __restrict__ gn1b,
                                               const float* __restrict__ stats,
                                               unsigned short* __restrict__ h1p,
                                               unsigned short* __restrict__ xdb,
                                               float* __restrict__ dm)
{
    int tid = threadIdx.x;
    int c  = tid & 63;
    int vl = tid >> 6;
    const size_t ovbase = (size_t)blockIdx.x * 32;
    const int b = (int)(ovbase >> 15);          // uniform per block (32768 % 32 == 0)

    int g = c >> 1;
    float ce   = fmaxf(stats[OFF_CNT1 + b] * 2.f, 1.f);
    float mean = stats[OFF_S1A + b * 32 + g] / ce;
    float var  = stats[OFF_S2A + b * 32 + g] / ce - mean * mean;
    float rinv = rsqrtf(var + 1e-5f);
    float a  = rinv * gn1w[c];
    float bc = gn1b[c] - mean * a;

    const int*   mb = mask + ((size_t)b << 18);
    const float* xb = x + (((size_t)b << 18) << 6);

    #pragma unroll 2
    for (int it = 0; it < 8; ++it) {
        size_t ov = ovbase + it * 4 + vl;
        int v2 = (int)(ov & 32767);
        int z = v2 >> 10, y = (v2 >> 5) & 31, xk = v2 & 31;

        float hacc = 0.f, xacc = 0.f; int cnt = 0;
        #pragma unroll
        for (int dz = 0; dz < 2; ++dz)
        #pragma unroll
        for (int dy = 0; dy < 2; ++dy)
        #pragma unroll
        for (int dx = 0; dx < 2; ++dx) {
            int v1 = ((2 * z + dz) << 12) | ((2 * y + dy) << 6) | (2 * xk + dx);
            if (mb[v1]) {
                cnt++;
                float xv = xb[(size_t)v1 * 64 + c];
                xacc += xv;
                hacc += fast_silu(fmaf(xv, a, bc));
            }
        }
        float inv = __builtin_amdgcn_rcpf(fmaxf((float)cnt, 1.f));
        int pvox = (z + 1) * P2_ + (y + 1) * P_ + (xk + 1);
        size_t so = ((size_t)(c >> 5) * SBSTRIDE + (size_t)b * P3_ + pvox) * 32 + (c & 31);
        h1p[so] = f2bf(hacc * inv);
        xdb[ov * 64 + c] = f2bf(xacc * inv);
        if (c == 0) dm[ov] = (cnt > 0) ? 1.f : 0.f;
    }
}

// ---------------- MFMA implicit-GEMM conv 3x3x3 (+optional 1x1 skip taps) ----------------
// Wave tile M=64 (2 y-rows) x N=128: acc[4][8] = 128 VGPR; 32 MFMA per K-step vs
// 8 ds_read_b128 -> LDS-read/MFMA ratio 0.25 (matrix-bound). Block = 4 waves =
// M=256 (8 y-rows at one (b,z)). BK=64 phases, W via global_load_lds (dbuf),
// counted vmcnt(8) keeps 8 A-loads in flight across the barrier; setprio on MFMA.
template<int CIN, bool SKIP>
__global__ __launch_bounds__(256, 2) void conv3_mfma(
    const unsigned short* __restrict__ srcP,   // padded [CS][4][34^3][32]
    const unsigned short* __restrict__ sksrc,  // flat [TOTV][64] (skip) or null
    const unsigned short* __restrict__ wT,
    const int* __restrict__ tblA,
    const float* __restrict__ bias,
    const float* __restrict__ bias2,
    const float* __restrict__ dm,
    float* __restrict__ outf,
    unsigned short* __restrict__ outb)
{
    constexpr int CS   = CIN / 32;
    constexpr int NKM  = 27 * CS;                 // main K-steps (even)
    constexpr int NPHM = NKM / 2;                 // main phases
    constexpr int NPH  = NPHM + (SKIP ? 1 : 0);   // total phases

    __shared__ short smem[2][8192];   // 2 x 16KB W slab-pairs

    const int tid  = threadIdx.x;
    const int lane = tid & 63;
    const int wv   = tid >> 6;
    // XCD-aware bijective swizzle: 512 blocks, 8 XCDs, 64-block chunks
    const int orig = blockIdx.x;
    const int blk  = (orig & 7) * 64 + (orig >> 3);
    const int b    = blk >> 7;
    const int z    = (blk >> 2) & 31;
    const int yo   = blk & 3;
    const int y0   = yo * 8 + wv * 2;  // this wave's first y-row (owns rows y0, y0+1)
    const int vb   = b * 32768;
    const int klo  = (lane >> 4) * 8;
    const int xl   = lane & 15;
    const int rlo  = (lane >> 4) * 4;

    f32x4 acc[4][8];
    #pragma unroll
    for (int f = 0; f < 4; ++f)
        #pragma unroll
        for (int nb = 0; nb < 8; ++nb)
            acc[f][nb] = (f32x4){0.f, 0.f, 0.f, 0.f};

    // per-lane A pointer at step 0 (tap dz=dy=dx=0, s=0): padded coords (z, y0, xl)
    const char* pA = (const char*)srcP +
        (((size_t)b * P3_ + (size_t)(z * P2_ + y0 * P_ + xl)) * 32 + klo) * 2;

    // skip-phase A loader (flat xdb, center tap, always in bounds): 4 frags
    auto loadSkip = [&](int ss, bf16x8* af) {
        const unsigned short* abase = sksrc + ss * 32;
        #pragma unroll
        for (int fy = 0; fy < 2; ++fy)
            #pragma unroll
            for (int fx = 0; fx < 2; ++fx)
                af[fy * 2 + fx] = *(const bf16x8*)(abase +
                    (size_t)(vb + z * 1024 + (y0 + fy) * 32 + fx * 16 + xl) * 64 + klo);
    };

    // stage W slab-pair `pr` into LDS buffer `buf` via global_load_lds (4 x 16B/thread)
    auto stageW = [&](int pr, int buf) {
        const char* g = (const char*)wT + (size_t)pr * 16384 + wv * 1024 + (lane << 4);
        char* l = (char*)&smem[0][0] + buf * 16384 + wv * 1024;
        #pragma unroll
        for (int j = 0; j < 4; ++j)
            __builtin_amdgcn_global_load_lds(
                (const __attribute__((address_space(1))) unsigned int*)(g + j * 4096),
                (__attribute__((address_space(3))) unsigned int*)(l + j * 4096),
                16, 0, 0);
    };

    // load A frags (4) for one main K-step at current pA, then advance
    auto loadAStep = [&](int ks, bf16x8* af) {
        af[0] = *(const bf16x8*)pA;
        af[1] = *(const bf16x8*)(pA + 1024);
        af[2] = *(const bf16x8*)(pA + 2176);
        af[3] = *(const bf16x8*)(pA + 3200);
        pA += tblA[ks];
    };

    // ---- prologue: W pair 0 -> LDS[0], A steps 0,1 -> afc ----
    bf16x8 afc[8];
    stageW(0, 0);
    loadAStep(0, &afc[0]);
    loadAStep(1, &afc[4]);
    asm volatile("s_waitcnt vmcnt(8)" ::: "memory");
    __builtin_amdgcn_s_barrier();

    int cur = 0;
    #pragma unroll 2
    for (int p = 0; p < NPH; ++p) {
        const bool more = (p + 1 < NPH);
        // issue-early: W pair p+1 -> LDS[cur^1]; A for phase p+1 -> afn
        bf16x8 afn[8] = {{}, {}, {}, {}, {}, {}, {}, {}};
        if (more) {
            stageW(p + 1, cur ^ 1);
            if (2 * p + 2 < NKM) {
                loadAStep(2 * p + 2, &afn[0]);
                loadAStep(2 * p + 3, &afn[4]);
            } else if (SKIP) {
                loadSkip(0, &afn[0]);
                loadSkip(1, &afn[4]);
            }
        }
        // MFMA cluster: 2 sub-steps x 8 n-frags x 4 m-frags = 64 MFMA
        __builtin_amdgcn_s_setprio(1);
        #pragma unroll
        for (int ss = 0; ss < 2; ++ss) {
            const short* bp = &smem[0][0] + cur * 8192 + ss * 4096 +
                              ((lane >> 4) * 128 + xl) * 8;
            #pragma unroll
            for (int nb = 0; nb < 8; ++nb) {
                bf16x8 bfr = *(const bf16x8*)(bp + nb * 128);
                acc[0][nb] = __builtin_amdgcn_mfma_f32_16x16x32_bf16(afc[ss * 4 + 0], bfr, acc[0][nb], 0, 0, 0);
                acc[1][nb] = __builtin_amdgcn_mfma_f32_16x16x32_bf16(afc[ss * 4 + 1], bfr, acc[1][nb], 0, 0, 0);
                acc[2][nb] = __builtin_amdgcn_mfma_f32_16x16x32_bf16(afc[ss * 4 + 2], bfr, acc[2][nb], 0, 0, 0);
                acc[3][nb] = __builtin_amdgcn_mfma_f32_16x16x32_bf16(afc[ss * 4 + 3], bfr, acc[3][nb], 0, 0, 0);
            }
        }
        __builtin_amdgcn_s_setprio(0);
        // counted drain: W gloads (oldest 4) done; 8 A loads stay in flight
        if (more) asm volatile("s_waitcnt vmcnt(8)" ::: "memory");
        else      asm volatile("s_waitcnt vmcnt(0)" ::: "memory");
        asm volatile("s_waitcnt lgkmcnt(0)" ::: "memory");
        __builtin_amdgcn_s_barrier();
        #pragma unroll
        for (int j = 0; j < 8; ++j) afc[j] = afn[j];
        cur ^= 1;
    }

    // ---- epilogue ----
    float bv[8];
    #pragma unroll
    for (int nb = 0; nb < 8; ++nb) {
        int co = nb * 16 + xl;
        if constexpr (SKIP) bv[nb] = bias[co] + bias2[co];
        else                bv[nb] = bias[co];
    }
    #pragma unroll
    for (int f = 0; f < 4; ++f) {
        const int fy = f >> 1, fx = f & 1;
        const int vox0 = vb + z * 1024 + (y0 + fy) * 32 + fx * 16 + rlo;
        float4 dm4 = *(const float4*)(dm + vox0);
        #pragma unroll
        for (int j = 0; j < 4; ++j) {
            const float dmx = (j == 0) ? dm4.x : (j == 1) ? dm4.y : (j == 2) ? dm4.z : dm4.w;
            const size_t obase = (size_t)(vox0 + j) * 128 + xl;
            #pragma unroll
            for (int nb = 0; nb < 8; ++nb) {
                float o = (acc[f][nb][j] + bv[nb]) * dmx;
                if constexpr (SKIP) outf[obase + nb * 16] = o;
                else                outb[obase + nb * 16] = f2bf(o);
            }
        }
    }
}

// ---------------- Kernel 4: GN2 stats over h2a (flat bf16) ----------------
__global__ __launch_bounds__(256) void k4_stats2(const unsigned short* __restrict__ h2a,
                                                 const float* __restrict__ dm,
                                                 float* __restrict__ stats)
{
    __shared__ float ls1[32], ls2[32];
    __shared__ float lcnt;
    int tid = threadIdx.x;
    if (tid < 32) { ls1[tid] = 0.f; ls2[tid] = 0.f; }
    if (tid == 0) lcnt = 0.f;
    __syncthreads();

    int b  = blockIdx.x & 3;
    int bb = blockIdx.x >> 2;
    int g  = tid & 31;
    int vl = tid >> 5;

    const unsigned short* hb = h2a + ((size_t)b * V2) * C2;
    const float* dmb = dm + (size_t)b * V2;

    float s1 = 0.f, s2 = 0.f, mc = 0.f;
    for (int ch = bb; ch < V2 / 8; ch += 1024) {
        int v = ch * 8 + vl;
        float m = dmb[v];
        if (g == 0) mc += m;
        if (m != 0.f) {
            ushort4 hv = *(const ushort4*)(hb + (size_t)v * C2 + g * 4);
            float h0 = bf2f(hv.x), h1 = bf2f(hv.y), h2 = bf2f(hv.z), h3 = bf2f(hv.w);
            s1 += h0 + h1 + h2 + h3;
            s2 += h0 * h0 + h1 * h1 + h2 * h2 + h3 * h3;
        }
    }
    atomicAdd(&ls1[g], s1); atomicAdd(&ls2[g], s2);
    if (g == 0) atomicAdd(&lcnt, mc);
    __syncthreads();
    if (tid < 32) {
        atomicAdd(&stats[OFF_S1B + b * 32 + tid], ls1[tid]);
        atomicAdd(&stats[OFF_S2B + b * 32 + tid], ls2[tid]);
    }
    if (tid == 0) atomicAdd(&stats[OFF_CNT2 + b], lcnt);
}

// ---------------- Kernel 5: GN2 apply + SiLU -> h2p (padded sliced bf16) ----------------
// grid 2048; 8 group-quads per thread (coalesced per iteration); stats hoisted.
__global__ __launch_bounds__(256) void k5_gn2(const unsigned short* __restrict__ h2a,
                                              unsigned short* __restrict__ h2p,
                                              const float* __restrict__ stats,
                                              const float* __restrict__ dm,
                                              const float* __restrict__ gn2w,
                                              const float* __restrict__ gn2b)
{
    int tid = threadIdx.x;
    int g = tid & 31;                               // loop-invariant (256 % 32 == 0)
    const int idx0 = blockIdx.x * 2048;
    const int b = (idx0 >> 5) >> 15;                // uniform per block

    float ce   = fmaxf(stats[OFF_CNT2 + b] * 4.f, 1.f);
    float mean = stats[OFF_S1B + b * 32 + g] / ce;
    float var  = stats[OFF_S2B + b * 32 + g] / ce - mean * mean;
    float rinv = rsqrtf(var + 1e-5f);
    float4 gw = *(const float4*)(gn2w + g * 4);
    float4 gb = *(const float4*)(gn2b + g * 4);
    float ax = rinv * gw.x, bx = gb.x - mean * ax;
    float ay = rinv * gw.y, by = gb.y - mean * ay;
    float az = rinv * gw.z, bz = gb.z - mean * az;
    float aw = rinv * gw.w, bw = gb.w - mean * aw;

    #pragma unroll 2
    for (int it = 0; it < 8; ++it) {
        int idx = idx0 + it * 256 + tid;
        int v = idx >> 5;
        int v2 = v & 32767;
        float dmv = dm[v];
        ushort4 hv = *(const ushort4*)(h2a + (size_t)idx * 4);
        float t;
        ushort4 o;
        t = fmaf(bf2f(hv.x), ax, bx) * dmv; o.x = f2bf(fast_silu(t));
        t = fmaf(bf2f(hv.y), ay, by) * dmv; o.y = f2bf(fast_silu(t));
        t = fmaf(bf2f(hv.z), az, bz) * dmv; o.z = f2bf(fast_silu(t));
        t = fmaf(bf2f(hv.w), aw, bw) * dmv; o.w = f2bf(fast_silu(t));
        int zz = v2 >> 10, yy = (v2 >> 5) & 31, xx = v2 & 31;
        int pvox = (zz + 1) * P2_ + (yy + 1) * P_ + (xx + 1);
        size_t so = ((size_t)(g >> 3) * SBSTRIDE + (size_t)b * P3_ + pvox) * 32 + (g & 7) * 4;
        *(ushort4*)(h2p + so) = o;
    }
}

extern "C" void kernel_launch(void* const* d_in, const int* in_sizes, int n_in,
                              void* d_out, int out_size, void* d_ws, size_t ws_size,
                              hipStream_t stream)
{
    const float* x     = (const float*)d_in[0];
    const int*   mask  = (const int*)d_in[1];
    const float* gn1w  = (const float*)d_in[2];
    const float* gn1b  = (const float*)d_in[3];
    const float* w1    = (const float*)d_in[4];
    const float* b1    = (const float*)d_in[5];
    const float* gn2w  = (const float*)d_in[6];
    const float* gn2b  = (const float*)d_in[7];
    const float* w2    = (const float*)d_in[8];
    const float* b2    = (const float*)d_in[9];
    const float* wskip = (const float*)d_in[10];
    const float* bskip = (const float*)d_in[11];
    float* out = (float*)d_out;

    char* wsb = (char*)d_ws;
    float*          stats = (float*)wsb;                           // 520 f32
    float*          dm    = (float*)(wsb + 4096);                  // 131072 f32
    unsigned short* h1p   = (unsigned short*)(wsb + 528384);       // 8 sb x 34^3 x 32
    unsigned short* xdb   = (unsigned short*)(wsb + 20652032);     // [TOTV][64]
    unsigned short* h2a   = (unsigned short*)(wsb + 37429248);     // [TOTV][128]
    unsigned short* h2p   = (unsigned short*)(wsb + 70983680);     // 16 sb x 34^3 x 32
    unsigned short* w1t   = (unsigned short*)(wsb + 111230976);    // 54*4096
    unsigned short* w2t   = (unsigned short*)(wsb + 111673344);    // 110*4096
    int*            d1    = (int*)(wsb + 112574464);               // 54 ints
    int*            d2    = (int*)(wsb + 112574720);               // 108 ints

    hipMemsetAsync(stats, 0, 520 * sizeof(float), stream);

    hipLaunchKernelGGL(k0z_prep, dim3(2624 + 3685), dim3(256), 0, stream,
                       w1, w2, wskip, w1t, w2t, d1, d2, h1p, h2p);
    hipLaunchKernelGGL(k1_stats1, dim3(4096), dim3(256), 0, stream, x, mask, stats);
    hipLaunchKernelGGL(k2_down, dim3(4096), dim3(256), 0, stream,
                       x, mask, gn1w, gn1b, stats, h1p, xdb, dm);
    hipLaunchKernelGGL((conv3_mfma<64, false>), dim3(512), dim3(256), 0, stream,
                       h1p, (const unsigned short*)nullptr, w1t, d1, b1, (const float*)nullptr,
                       dm, (float*)nullptr, h2a);
    hipLaunchKernelGGL(k4_stats2, dim3(4096), dim3(256), 0, stream, h2a, dm, stats);
    hipLaunchKernelGGL(k5_gn2, dim3(2048), dim3(256), 0, stream, h2a, h2p, stats, dm, gn2w, gn2b);
    hipLaunchKernelGGL((conv3_mfma<128, true>), dim3(512), dim3(256), 0, stream,
                       h2p, xdb, w2t, d2, b2, bskip, dm, out, (unsigned short*)nullptr);
}